// Round 11
// baseline (1250.141 us; speedup 1.0000x reference)
//
#include <hip/hip_runtime.h>
#include <math.h>

typedef unsigned int   u32;
typedef unsigned short u16;
typedef __attribute__((ext_vector_type(8))) short bf16x8;
typedef __attribute__((ext_vector_type(4))) float f32x4;
typedef __attribute__((ext_vector_type(4))) unsigned short u16x4;
typedef __attribute__((ext_vector_type(8))) unsigned short u16x8;

#define HID   768
#define SEQ   512
#define BATCH 8
#define LAYERS 8
#define VOC   10000
#define NROWS (BATCH*SEQ)             // 4096
#define NH    ((long long)NROWS*HID)  // 3,145,728
#define SS8   ((long long)BATCH*SEQ*SEQ)
#define EPSLN 1e-5f
#define WSZ   ((long long)HID*HID)    // 589824

__device__ __forceinline__ u16 f2bf(float f) {
    u32 u = __builtin_bit_cast(u32, f);
    return (u16)((u + 0x7fffu + ((u >> 16) & 1u)) >> 16);
}
__device__ __forceinline__ float bf2f(u16 h) {
    return __builtin_bit_cast(float, (u32)h << 16);
}

__device__ __forceinline__ void async16(u16* lds, const u16* g) {
    __builtin_amdgcn_global_load_lds(
        (const __attribute__((address_space(1))) u32*)g,
        (__attribute__((address_space(3))) u32*)lds, 16, 0, 0);
}

// ---- embedding + positional encoding (fp32 + bf16 shadow) ---------------
__global__ __launch_bounds__(256) void embed_kernel(
    const int* __restrict__ x, const float* __restrict__ emb,
    float* __restrict__ Z, u16* __restrict__ Zh)
{
    const int row = blockIdx.x;
    const int s   = row & (SEQ - 1);
    const int tok = x[row];
    const long long base  = (long long)row * HID;
    const long long ebase = (long long)tok * HID;
    const float coef = -0.0239852613853544f;   // -2*ln(10000)/768
    #pragma unroll
    for (int j = 0; j < 3; ++j) {
        const int h = threadIdx.x + 256 * j;
        const int i = h >> 1;
        const float ang = (float)s * expf((float)i * coef);
        const float pe  = (h & 1) ? cosf(ang) : sinf(ang);
        const float v = emb[ebase + h] + pe;
        Z[base + h]  = v;
        Zh[base + h] = f2bf(v);
    }
}

// ---- emb fp32 -> bf16, vectorized --------------------------------------
__global__ __launch_bounds__(256) void convert_emb(
    const float* __restrict__ e, u16* __restrict__ eh)
{
    const long long i = ((long long)blockIdx.x * 256 + threadIdx.x) * 4;
    const float4 v = *(const float4*)&e[i];
    u16x4 p;
    p[0] = f2bf(v.x); p[1] = f2bf(v.y); p[2] = f2bf(v.z); p[3] = f2bf(v.w);
    *(u16x4*)&eh[i] = p;
}

// ---- all-weights transpose+convert: fp32 [K,N] -> bf16 [N,K] ------------
__global__ __launch_bounds__(256) void transp_all(
    const float* __restrict__ Wq, const float* __restrict__ Wk,
    const float* __restrict__ Wv, const float* __restrict__ W1,
    const float* __restrict__ W2, const float* __restrict__ fcw,
    u16* __restrict__ WT)
{
    __shared__ u16 tile[32][34];
    const int z = blockIdx.z;
    const float* src;
    long long doff;
    if (z < 40) {
        const int lyr = z / 5, idx = z % 5;
        const float* bases[5] = {Wq, Wk, Wv, W1, W2};
        src  = bases[idx] + (long long)lyr * WSZ;
        doff = ((long long)lyr * 5 + idx) * WSZ;
    } else {
        src = fcw; doff = 40LL * WSZ;
    }
    u16* D = WT + doff;
    const int n0 = blockIdx.x * 32, k0 = blockIdx.y * 32;
    const int c = threadIdx.x & 31, r0 = threadIdx.x >> 5;
    #pragma unroll
    for (int p = 0; p < 4; ++p)
        tile[r0 + 8*p][c] = f2bf(src[(long long)(k0 + r0 + 8*p) * HID + n0 + c]);
    __syncthreads();
    #pragma unroll
    for (int p = 0; p < 4; ++p)
        D[(long long)(n0 + r0 + 8*p) * HID + k0 + c] = tile[c][r0 + 8*p];
}

// ---- pack qkv biases: [L][3*768] ---------------------------------------
__global__ void pack_bias_all(const float* __restrict__ bq,
                              const float* __restrict__ bk,
                              const float* __restrict__ bv,
                              float* __restrict__ dst)
{
    const int part = blockIdx.x, l = blockIdx.y, h = threadIdx.x;
    const float* src = part == 0 ? bq : (part == 1 ? bk : bv);
    dst[((long long)l*3 + part) * HID + h] = src[(long long)l*HID + h];
}

// ---- deep 8-phase GEMM: BMx256, BK=64 (2 k-halves), 8 waves (2M x 4N) ---
// Depth-3 half-tile prefetch (T3+T4): prologue stages halves 0,1,2; phase
// ph waits vmcnt(2*(MF+2)) (oldest = its own half), barrier, stages half
// ph+3 into slot (ph+3)%4 (readers passed 2 barriers ago). vmcnt drains
// 2L->L->0 only in the last two phases. Swizzle: LDS[row][slot j] holds
// global k-slot j^((row>>1)&3) (stage source pre-swizzled, dest linear,
// read un-swizzles) -- r7-verified conflict-free + correct.
// VSPLIT: cols<1536 -> Cp (ldc), cols>=1536 transposed to vt[b][col-1536][s].
template<int BM, bool VSPLIT>
__global__ __launch_bounds__(512) void gemm_8ph(
    const u16* __restrict__ A, const u16* __restrict__ B,
    u16* __restrict__ Cp, int ldc, int N, int K,
    const float* __restrict__ bias, u16* __restrict__ vt)
{
    constexpr int MF = BM / 128;          // A stage-instr per half per thread
    constexpr int MI = BM / 32;           // A frags per wave per half
    __shared__ u16 Ab[2][2][BM * 32];
    __shared__ u16 Bb[2][2][256 * 32];
    const int m0 = blockIdx.x * BM;
    const int n0 = blockIdx.y * 256;
    const int t = threadIdx.x, w = t >> 6, l = t & 63;
    const int fr = l & 15, jl = l >> 4;
    const int wm = (w >> 2) * (BM / 2), wn = (w & 3) * 64;

    f32x4 acc[MI][4];
    #pragma unroll
    for (int mf = 0; mf < MI; ++mf)
        #pragma unroll
        for (int nf = 0; nf < 4; ++nf) acc[mf][nf] = (f32x4){0.f,0.f,0.f,0.f};

    auto stageA = [&](int g) {
        const int d = (g >> 1) & 1, h = g & 1, kt = (g >> 1) << 6;
        #pragma unroll
        for (int r = 0; r < MF; ++r) {
            const int c = r * 512 + t;
            const int row = c >> 2, j = c & 3;
            const int kof = kt + h * 32 + ((j ^ ((row >> 1) & 3)) << 3);
            async16(&Ab[d][h][c * 8], A + (long long)(m0 + row) * K + kof);
        }
    };
    auto stageB = [&](int g) {
        const int d = (g >> 1) & 1, h = g & 1, kt = (g >> 1) << 6;
        #pragma unroll
        for (int r = 0; r < 2; ++r) {
            const int c = r * 512 + t;
            const int row = c >> 2, j = c & 3;
            int gr = n0 + row; gr = gr < N ? gr : N - 1;
            const int kof = kt + h * 32 + ((j ^ ((row >> 1) & 3)) << 3);
            async16(&Bb[d][h][c * 8], B + (long long)gr * K + kof);
        }
    };

    const int P = K >> 5;                 // halves (24 at K=768)
    stageA(0); stageB(0); stageA(1); stageB(1); stageA(2); stageB(2);
    for (int ph = 0; ph < P; ++ph) {
        const int rem = P - 1 - ph;
        if (rem >= 2)
            asm volatile("s_waitcnt vmcnt(%0)" :: "i"(2 * (MF + 2)) : "memory");
        else if (rem == 1)
            asm volatile("s_waitcnt vmcnt(%0)" :: "i"(MF + 2) : "memory");
        else
            asm volatile("s_waitcnt vmcnt(0)" ::: "memory");
        __builtin_amdgcn_s_barrier();
        if (ph + 3 < P) { stageA(ph + 3); stageB(ph + 3); }
        const int d = (ph >> 1) & 1, h = ph & 1;
        bf16x8 bfr[4], af[MI];
        #pragma unroll
        for (int nf = 0; nf < 4; ++nf) {
            const int row = wn + nf * 16 + fr;
            bfr[nf] = *(const bf16x8*)
                &Bb[d][h][row * 32 + ((jl ^ ((row >> 1) & 3)) << 3)];
        }
        #pragma unroll
        for (int mf = 0; mf < MI; ++mf) {
            const int row = wm + mf * 16 + fr;
            af[mf] = *(const bf16x8*)
                &Ab[d][h][row * 32 + ((jl ^ ((row >> 1) & 3)) << 3)];
        }
        __builtin_amdgcn_s_setprio(1);
        #pragma unroll
        for (int mf = 0; mf < MI; ++mf)
            #pragma unroll
            for (int nf = 0; nf < 4; ++nf)
                acc[mf][nf] = __builtin_amdgcn_mfma_f32_16x16x32_bf16(
                    af[mf], bfr[nf], acc[mf][nf], 0, 0, 0);
        __builtin_amdgcn_s_setprio(0);
    }

    #pragma unroll
    for (int nf = 0; nf < 4; ++nf) {
        const int col = n0 + wn + nf * 16 + fr;
        if (col >= N) continue;
        const float bv = bias ? bias[col] : 0.f;
        #pragma unroll
        for (int mf = 0; mf < MI; ++mf) {
            const int row0 = m0 + wm + mf * 16 + jl * 4;
            if constexpr (VSPLIT) {
                if (col < 1536) {
                    #pragma unroll
                    for (int v = 0; v < 4; ++v)
                        Cp[(long long)(row0 + v) * ldc + col] =
                            f2bf(acc[mf][nf][v] + bv);
                } else {
                    const int b9 = row0 >> 9, s9 = row0 & 511;
                    u16x4 pk;
                    #pragma unroll
                    for (int v = 0; v < 4; ++v)
                        pk[v] = f2bf(acc[mf][nf][v] + bv);
                    *(u16x4*)&vt[((long long)b9 * HID + (col - 1536)) * SEQ + s9] = pk;
                }
            } else {
                #pragma unroll
                for (int v = 0; v < 4; ++v)
                    Cp[(long long)(row0 + v) * ldc + col] =
                        f2bf(acc[mf][nf][v] + bv);
            }
        }
    }
}

// ---- small MFMA GEMM: BM=BN=64, BK=64, 2 waves, XOR-swizzled LDS --------
template<bool RELU, bool OUT_BF16>
__global__ __launch_bounds__(128) void gemm_small(
    const u16* __restrict__ A, int lda, long long sA,
    const u16* __restrict__ B, int ldb, long long sB,
    void* __restrict__ Cp, int ldc, long long sC,
    int N, int K, const float* __restrict__ bias, float alpha)
{
    __shared__ u16 As[2][64 * 64];
    __shared__ u16 Bs[2][64 * 64];
    const int bz = blockIdx.z;
    const int n0 = blockIdx.x * 64;
    const int m0 = blockIdx.y * 64;
    const int t = threadIdx.x, w = t >> 6, l = t & 63;
    const int srow = l >> 3;                  // row within 8-row seg
    const int skof = ((l & 7) ^ srow) * 8;    // pre-swizzled global k-slot
    const int wm = w * 32;
    A += sA * bz; B += sB * bz;

    f32x4 acc[2][4];
    #pragma unroll
    for (int mi = 0; mi < 2; ++mi)
        #pragma unroll
        for (int ni = 0; ni < 4; ++ni) acc[mi][ni] = (f32x4){0.f,0.f,0.f,0.f};

    auto stage = [&](int buf, int k0) {
        #pragma unroll
        for (int r = 0; r < 4; ++r) {
            const int seg = w * 4 + r;
            const int row = seg * 8 + srow;
            async16(&As[buf][seg * 512],
                    A + (long long)(m0 + row) * lda + (k0 + skof));
        }
        #pragma unroll
        for (int r = 0; r < 4; ++r) {
            const int seg = w * 4 + r;
            const int row = seg * 8 + srow;
            async16(&Bs[buf][seg * 512],
                    B + (long long)(n0 + row) * ldb + (k0 + skof));
        }
    };
    const int fr = l & 15, fkb = l >> 4;      // logical slot base 0..3
    auto compute = [&](int cur) {
        #pragma unroll
        for (int ks = 0; ks < 2; ++ks) {
            const int ps = ((ks * 4 + fkb) ^ (fr & 7)) * 8;
            bf16x8 af[2], bfv[4];
            #pragma unroll
            for (int mi = 0; mi < 2; ++mi)
                af[mi] = *(const bf16x8*)&As[cur][(wm + mi*16 + fr) * 64 + ps];
            #pragma unroll
            for (int ni = 0; ni < 4; ++ni)
                bfv[ni] = *(const bf16x8*)&Bs[cur][(ni*16 + fr) * 64 + ps];
            #pragma unroll
            for (int mi = 0; mi < 2; ++mi)
                #pragma unroll
                for (int ni = 0; ni < 4; ++ni)
                    acc[mi][ni] = __builtin_amdgcn_mfma_f32_16x16x32_bf16(
                        af[mi], bfv[ni], acc[mi][ni], 0, 0, 0);
        }
    };

    const int NS = K >> 6;                    // 12 (K=768) or 8 (K=512)
    stage(0, 0);
    for (int tt = 0; tt < NS; ++tt) {
        if (tt + 1 < NS) {
            stage((tt + 1) & 1, (tt + 1) << 6);
            asm volatile("s_waitcnt vmcnt(8)\n\ts_barrier" ::: "memory");
        } else {
            asm volatile("s_waitcnt vmcnt(0)\n\ts_barrier" ::: "memory");
        }
        compute(tt & 1);
        asm volatile("s_barrier" ::: "memory");
    }

    float* Cf = (float*)Cp + sC * bz;
    u16*   Ch = (u16*)Cp + sC * bz;
    const int fq = l >> 4;
    #pragma unroll
    for (int ni = 0; ni < 4; ++ni) {
        const int col = n0 + ni*16 + fr;
        const float bv = bias ? bias[col] : 0.f;
        #pragma unroll
        for (int mi = 0; mi < 2; ++mi) {
            const int row0 = m0 + wm + mi*16 + fq*4;
            #pragma unroll
            for (int v = 0; v < 4; ++v) {
                float val = alpha * acc[mi][ni][v] + bv;
                if (RELU) val = fmaxf(val, 0.f);
                if (OUT_BF16) Ch[(long long)(row0 + v) * ldc + col] = f2bf(val);
                else          Cf[(long long)(row0 + v) * ldc + col] = val;
            }
        }
    }
}

// ---- fallback logits GEMM (fp32 B converted in-flight) -> bf16 out ------
__global__ __launch_bounds__(256) void gemm_conv(
    const u16* __restrict__ A, const float* __restrict__ Bf,
    u16* __restrict__ C)  // C = (u16*)out + VOC, ldc 2*VOC
{
    __shared__ u16 As[128 * 32];
    __shared__ u16 Bs[128 * 32];
    const int m0 = blockIdx.x * 128;
    const int n0 = blockIdx.y * 128;
    const int t = threadIdx.x, w = t >> 6, l = t & 63;
    const int lrow = l >> 2, lk8 = (l & 3) * 8;
    const int wm = (w >> 1) * 64, wn = (w & 1) * 64;
    f32x4 acc[4][4];
    #pragma unroll
    for (int mi = 0; mi < 4; ++mi)
        #pragma unroll
        for (int ni = 0; ni < 4; ++ni) acc[mi][ni] = (f32x4){0.f,0.f,0.f,0.f};

    for (int k0 = 0; k0 < HID; k0 += 32) {
        #pragma unroll
        for (int r = 0; r < 2; ++r) {
            const int seg = w * 2 + r;
            async16(&As[seg * 512],
                    A + (long long)(m0 + seg*16 + lrow) * HID + (k0 + lk8));
        }
        #pragma unroll
        for (int r = 0; r < 2; ++r) {
            const int flat = r * 2048 + t * 8;
            int row = n0 + (flat >> 5);
            row = row < VOC ? row : VOC - 1;
            const float* g = Bf + (long long)row * HID + (k0 + (flat & 31));
            const float4 v0 = *(const float4*)g;
            const float4 v1 = *(const float4*)(g + 4);
            bf16x8 hv;
            hv[0]=(short)f2bf(v0.x); hv[1]=(short)f2bf(v0.y);
            hv[2]=(short)f2bf(v0.z); hv[3]=(short)f2bf(v0.w);
            hv[4]=(short)f2bf(v1.x); hv[5]=(short)f2bf(v1.y);
            hv[6]=(short)f2bf(v1.z); hv[7]=(short)f2bf(v1.w);
            *(bf16x8*)&Bs[flat] = hv;
        }
        __syncthreads();
        const int fr = l & 15, fk = (l >> 4) * 8;
        bf16x8 af[4], bfr[4];
        #pragma unroll
        for (int mi = 0; mi < 4; ++mi)
            af[mi] = *(const bf16x8*)&As[(wm + mi*16 + fr) * 32 + fk];
        #pragma unroll
        for (int ni = 0; ni < 4; ++ni)
            bfr[ni] = *(const bf16x8*)&Bs[(wn + ni*16 + fr) * 32 + fk];
        #pragma unroll
        for (int mi = 0; mi < 4; ++mi)
            #pragma unroll
            for (int ni = 0; ni < 4; ++ni)
                acc[mi][ni] = __builtin_amdgcn_mfma_f32_16x16x32_bf16(
                    af[mi], bfr[ni], acc[mi][ni], 0, 0, 0);
        __syncthreads();
    }
    const int fr = l & 15, fq = l >> 4;
    #pragma unroll
    for (int ni = 0; ni < 4; ++ni) {
        const int col = n0 + wn + ni*16 + fr;
        if (col >= VOC) continue;
        #pragma unroll
        for (int mi = 0; mi < 4; ++mi) {
            const int row0 = m0 + wm + mi*16 + fq*4;
            #pragma unroll
            for (int v = 0; v < 4; ++v)
                C[(long long)(row0 + v) * (2*VOC) + col] = f2bf(acc[mi][ni][v]);
        }
    }
}

// ---- masked softmax over QUERY axis (dim=1): fp32 in, bf16 out ----------
__global__ __launch_bounds__(256) void softmax_q_kernel(
    const float* __restrict__ sc, u16* __restrict__ att,
    const int* __restrict__ lengths)
{
    const int b  = blockIdx.x;
    const int k0 = blockIdx.y * 16;
    const int tx = threadIdx.x & 15;
    const int ty = threadIdx.x >> 4;
    const int c  = k0 + tx;
    const int len = lengths[b];
    const float* base  = sc  + (long long)b * SEQ * SEQ;
    u16*         obase = att + (long long)b * SEQ * SEQ;
    const bool cvalid = (c < len);

    float vals[32];
    float m = -3.0e38f, ssum = 0.f;
    #pragma unroll
    for (int i = 0; i < 32; ++i) {
        const int q = ty + 16 * i;
        float xv = -3.0e38f;
        if (cvalid && c <= q && q < len)
            xv = base[(long long)q * SEQ + c];
        vals[i] = xv;
        if (xv > m) { ssum = ssum * __expf(m - xv) + 1.f; m = xv; }
        else if (xv > -3.0e38f) { ssum += __expf(xv - m); }
    }
    __shared__ float ms[16][17], ss[16][17];
    ms[ty][tx] = m; ss[ty][tx] = ssum;
    __syncthreads();
    if (ty == 0) {
        float M = ms[0][tx];
        #pragma unroll
        for (int r = 1; r < 16; ++r) M = fmaxf(M, ms[r][tx]);
        float Sx = 0.f;
        #pragma unroll
        for (int r = 0; r < 16; ++r) Sx += ss[r][tx] * __expf(ms[r][tx] - M);
        ms[0][tx] = M; ss[0][tx] = Sx;
    }
    __syncthreads();
    const float M   = ms[0][tx];
    const float den = ss[0][tx];
    const float inv = (den > 0.f) ? 1.f / den : 0.f;
    #pragma unroll
    for (int i = 0; i < 32; ++i) {
        const int q = ty + 16 * i;
        obase[(long long)q * SEQ + c] = f2bf(__expf(vals[i] - M) * inv);
    }
}

// ---- fused residual-add + LayerNorm: wave-per-row, float4, no barriers --
__global__ __launch_bounds__(256) void ln_add_kernel(
    const float* __restrict__ Xa, const float* __restrict__ Xb,
    float* __restrict__ O, u16* __restrict__ Oh,
    const float* __restrict__ g, const float* __restrict__ be)
{
    const int row = blockIdx.x * 4 + (threadIdx.x >> 6);
    const int l = threadIdx.x & 63;
    const long long base = (long long)row * HID;
    float x[12];
    #pragma unroll
    for (int c = 0; c < 3; ++c) {
        const int off = c * 256 + l * 4;
        const float4 a = *(const float4*)&Xa[base + off];
        const float4 b = *(const float4*)&Xb[base + off];
        x[c*4+0] = a.x + b.x; x[c*4+1] = a.y + b.y;
        x[c*4+2] = a.z + b.z; x[c*4+3] = a.w + b.w;
    }
    float s = 0.f;
    #pragma unroll
    for (int i = 0; i < 12; ++i) s += x[i];
    #pragma unroll
    for (int o = 32; o; o >>= 1) s += __shfl_xor(s, o, 64);
    const float mean = s * (1.f / HID);
    float v = 0.f;
    #pragma unroll
    for (int i = 0; i < 12; ++i) { const float d = x[i] - mean; v += d * d; }
    #pragma unroll
    for (int o = 32; o; o >>= 1) v += __shfl_xor(v, o, 64);
    const float rs = rsqrtf(v * (1.f / HID) + EPSLN);
    #pragma unroll
    for (int c = 0; c < 3; ++c) {
        const int off = c * 256 + l * 4;
        const float4 gg = *(const float4*)&g[off];
        const float4 bb = *(const float4*)&be[off];
        float4 y;
        y.x = (x[c*4+0] - mean) * rs * gg.x + bb.x;
        y.y = (x[c*4+1] - mean) * rs * gg.y + bb.y;
        y.z = (x[c*4+2] - mean) * rs * gg.z + bb.z;
        y.w = (x[c*4+3] - mean) * rs * gg.w + bb.w;
        *(float4*)&O[base + off] = y;
        u16x4 p;
        p[0] = f2bf(y.x); p[1] = f2bf(y.y); p[2] = f2bf(y.z); p[3] = f2bf(y.w);
        *(u16x4*)&Oh[base + off] = p;
    }
}

// ---- vocab softmax: bf16 logits in (row-local upper half), fp32 out -----
__global__ __launch_bounds__(256) void softmax_v_kernel(float* __restrict__ out)
{
    __shared__ float row[VOC];            // 40 KB
    __shared__ float rm[4], rs_[4];
    const long long obase = (long long)blockIdx.x * VOC;
    const u16* lg = (const u16*)out + 2 * obase + VOC;  // bf16 logits row
    const int t = threadIdx.x;
    float m = -3.0e38f, s = 0.f;
    for (int i = t * 8; i < VOC; i += 2048) {
        const u16x8 h8 = *(const u16x8*)&lg[i];
        #pragma unroll
        for (int j = 0; j < 8; ++j) {
            const float xv = bf2f(h8[j]);
            row[i + j] = xv;
            const float d = xv - m;
            if (d > 0.f) { s = s * __expf(-d) + 1.f; m = xv; }
            else         { s += __expf(d); }
        }
    }
    #pragma unroll
    for (int o = 32; o; o >>= 1) {
        const float om = __shfl_down(m, o, 64), os = __shfl_down(s, o, 64);
        const float M = fmaxf(m, om);
        s = s * __expf(m - M) + os * __expf(om - M);
        m = M;
    }
    if ((t & 63) == 0) { rm[t >> 6] = m; rs_[t >> 6] = s; }
    __syncthreads();
    const float M = fmaxf(fmaxf(rm[0], rm[1]), fmaxf(rm[2], rm[3]));
    const float S = rs_[0]*__expf(rm[0]-M) + rs_[1]*__expf(rm[1]-M)
                  + rs_[2]*__expf(rm[2]-M) + rs_[3]*__expf(rm[3]-M);
    const float inv = 1.f / S;
    for (int i = t * 4; i < VOC; i += 1024) {
        float4 v = *(const float4*)&row[i];
        v.x = __expf(v.x - M) * inv;
        v.y = __expf(v.y - M) * inv;
        v.z = __expf(v.z - M) * inv;
        v.w = __expf(v.w - M) * inv;
        *(float4*)&out[obase + i] = v;
    }
}

// ---- host-side orchestration -------------------------------------------
extern "C" void kernel_launch(void* const* d_in, const int* in_sizes, int n_in,
                              void* d_out, int out_size, void* d_ws, size_t ws_size,
                              hipStream_t stream)
{
    const int*   x    = (const int*)  d_in[0];
    const int*   lens = (const int*)  d_in[1];
    const float* emb  = (const float*)d_in[2];
    const float* Wq   = (const float*)d_in[3];
    const float* bq   = (const float*)d_in[4];
    const float* Wk   = (const float*)d_in[5];
    const float* bk   = (const float*)d_in[6];
    const float* Wv   = (const float*)d_in[7];
    const float* bv   = (const float*)d_in[8];
    const float* W1   = (const float*)d_in[9];
    const float* b1   = (const float*)d_in[10];
    const float* W2   = (const float*)d_in[11];
    const float* b2   = (const float*)d_in[12];
    const float* g1   = (const float*)d_in[13];
    const float* be1  = (const float*)d_in[14];
    const float* g2   = (const float*)d_in[15];
    const float* be2  = (const float*)d_in[16];
    const float* fcw  = (const float*)d_in[17];
    const float* fcb  = (const float*)d_in[18];

    float* out = (float*)d_out;
    float* Zb     = out;
    float* O1f    = Zb + NH;
    float* M2f    = O1f + NH;
    float* SCORES = M2f + NH;
    float* BQKV   = SCORES + SS8;                   // [L][2304]
    u16* ub   = (u16*)(BQKV + (long long)LAYERS * 2304);
    u16* Zbh  = ub;  ub += NH;
    u16* QKVh = ub;  ub += (long long)NROWS * 1536; // Q|K, ldc 1536
    u16* ATTB = ub;  ub += SS8;
    u16* Vt   = ub;  ub += NH;                      // [B][H][S]
    u16* O1h  = ub;  ub += NH;
    u16* M1h  = ub;  ub += NH;
    u16* WT   = ub;  ub += 41LL * WSZ;

    u16* ZFh = (u16*)d_ws;
    u16* EH  = ZFh + NH;
    const bool ehpath = ws_size >= (size_t)((NH + (long long)VOC * HID) * 2);
    u16* LOGH = (u16*)out + VOC;                    // bf16 logits, ldc 2*VOC

    const float scale = 1.0f / sqrtf((float)HID);
    const dim3 blk(256), blk128(128), blk512(512);

    embed_kernel<<<NROWS, blk, 0, stream>>>(x, emb, Zb, Zbh);
    transp_all<<<dim3(24, 24, 41), blk, 0, stream>>>(Wq, Wk, Wv, W1, W2, fcw, WT);
    pack_bias_all<<<dim3(3, LAYERS), dim3(768), 0, stream>>>(bq, bk, bv, BQKV);
    if (ehpath) convert_emb<<<7500, blk, 0, stream>>>(emb, EH);

    for (int l = 0; l < LAYERS; ++l) {
        const u16* wl = WT + (long long)l * 5 * WSZ;

        // qkv: Q,K -> QKVh[4096][1536]; V -> Vt transposed. deep 8-phase,
        // BM=128 x BN=256, grid 32x9 = 288 blocks (full chip).
        gemm_8ph<128, true><<<dim3(32, 9), blk512, 0, stream>>>(
            Zbh, wl, QKVh, 1536, 2304, HID,
            BQKV + (long long)l * 2304, Vt);

        // scores = scale * Q @ K^T
        gemm_small<false, false><<<dim3(8, 8, BATCH), blk128, 0, stream>>>(
            QKVh, 1536, (long long)SEQ * 1536,
            QKVh + 768, 1536, (long long)SEQ * 1536,
            SCORES, SEQ, (long long)SEQ * SEQ,
            512, HID, nullptr, scale);

        softmax_q_kernel<<<dim3(BATCH, SEQ/16), blk, 0, stream>>>(SCORES, ATTB, lens);

        // attnout = att @ V
        gemm_small<false, false><<<dim3(12, 8, BATCH), blk128, 0, stream>>>(
            ATTB, SEQ, (long long)SEQ * SEQ,
            Vt, SEQ, (long long)HID * SEQ,
            O1f, HID, (long long)SEQ * HID,
            768, SEQ, nullptr, 1.0f);

        ln_add_kernel<<<NROWS/4, blk, 0, stream>>>(Zb, O1f, O1f, O1h,
                                                   g1 + l*HID, be1 + l*HID);
        gemm_small<true, true><<<dim3(12, 64), blk128, 0, stream>>>(
            O1h, HID, 0, wl + 3*WSZ, HID, 0, M1h, HID, 0,
            768, HID, b1 + l*HID, 1.0f);
        gemm_small<false, false><<<dim3(12, 64), blk128, 0, stream>>>(
            M1h, HID, 0, wl + 4*WSZ, HID, 0, M2f, HID, 0,
            768, HID, b2 + l*HID, 1.0f);
        ln_add_kernel<<<NROWS/4, blk, 0, stream>>>(M2f, O1f, Zb, Zbh,
                                                   g2 + l*HID, be2 + l*HID);
    }

    // fc: zf = z @ fc_w + fc_b -> bf16 in d_ws
    gemm_small<false, true><<<dim3(12, 64), blk128, 0, stream>>>(
        Zbh, HID, 0, WT + 40LL*WSZ, HID, 0, ZFh, HID, 0,
        768, HID, fcb, 1.0f);

    // logits = zf @ emb^T -> bf16, row-local upper half of d_out.
    // deep 8-phase, BM=256 x BN=256, grid 16x40 = 640 blocks.
    if (ehpath) {
        gemm_8ph<256, false><<<dim3(16, 40), blk512, 0, stream>>>(
            ZFh, EH, LOGH, 2*VOC, VOC, HID, nullptr, nullptr);
    } else {
        gemm_conv<<<dim3(32, 79), blk, 0, stream>>>(ZFh, emb, LOGH);
    }

    softmax_v_kernel<<<NROWS, blk, 0, stream>>>(out);
}

// Round 12
// 1098.117 us; speedup vs baseline: 1.1384x; 1.1384x over previous
//
#include <hip/hip_runtime.h>
#include <math.h>

typedef unsigned int   u32;
typedef unsigned short u16;
typedef __attribute__((ext_vector_type(8))) short bf16x8;
typedef __attribute__((ext_vector_type(4))) float f32x4;
typedef __attribute__((ext_vector_type(4))) unsigned short u16x4;
typedef __attribute__((ext_vector_type(8))) unsigned short u16x8;

#define HID   768
#define SEQ   512
#define BATCH 8
#define LAYERS 8
#define VOC   10000
#define NROWS (BATCH*SEQ)             // 4096
#define NH    ((long long)NROWS*HID)  // 3,145,728
#define SS8   ((long long)BATCH*SEQ*SEQ)
#define EPSLN 1e-5f
#define WSZ   ((long long)HID*HID)    // 589824

__device__ __forceinline__ u16 f2bf(float f) {
    u32 u = __builtin_bit_cast(u32, f);
    return (u16)((u + 0x7fffu + ((u >> 16) & 1u)) >> 16);
}
__device__ __forceinline__ float bf2f(u16 h) {
    return __builtin_bit_cast(float, (u32)h << 16);
}

__device__ __forceinline__ void async16(u16* lds, const u16* g) {
    __builtin_amdgcn_global_load_lds(
        (const __attribute__((address_space(1))) u32*)g,
        (__attribute__((address_space(3))) u32*)lds, 16, 0, 0);
}

// ---- embedding + positional encoding (fp32 + bf16 shadow) ---------------
__global__ __launch_bounds__(256) void embed_kernel(
    const int* __restrict__ x, const float* __restrict__ emb,
    float* __restrict__ Z, u16* __restrict__ Zh)
{
    const int row = blockIdx.x;
    const int s   = row & (SEQ - 1);
    const int tok = x[row];
    const long long base  = (long long)row * HID;
    const long long ebase = (long long)tok * HID;
    const float coef = -0.0239852613853544f;   // -2*ln(10000)/768
    #pragma unroll
    for (int j = 0; j < 3; ++j) {
        const int h = threadIdx.x + 256 * j;
        const int i = h >> 1;
        const float ang = (float)s * expf((float)i * coef);
        const float pe  = (h & 1) ? cosf(ang) : sinf(ang);
        const float v = emb[ebase + h] + pe;
        Z[base + h]  = v;
        Zh[base + h] = f2bf(v);
    }
}

// ---- emb fp32 -> bf16, vectorized --------------------------------------
__global__ __launch_bounds__(256) void convert_emb(
    const float* __restrict__ e, u16* __restrict__ eh)
{
    const long long i = ((long long)blockIdx.x * 256 + threadIdx.x) * 4;
    const float4 v = *(const float4*)&e[i];
    u16x4 p;
    p[0] = f2bf(v.x); p[1] = f2bf(v.y); p[2] = f2bf(v.z); p[3] = f2bf(v.w);
    *(u16x4*)&eh[i] = p;
}

// ---- all-weights transpose+convert: fp32 [K,N] -> bf16 [N,K] ------------
__global__ __launch_bounds__(256) void transp_all(
    const float* __restrict__ Wq, const float* __restrict__ Wk,
    const float* __restrict__ Wv, const float* __restrict__ W1,
    const float* __restrict__ W2, const float* __restrict__ fcw,
    u16* __restrict__ WT)
{
    __shared__ u16 tile[32][34];
    const int z = blockIdx.z;
    const float* src;
    long long doff;
    if (z < 40) {
        const int lyr = z / 5, idx = z % 5;
        const float* bases[5] = {Wq, Wk, Wv, W1, W2};
        src  = bases[idx] + (long long)lyr * WSZ;
        doff = ((long long)lyr * 5 + idx) * WSZ;
    } else {
        src = fcw; doff = 40LL * WSZ;
    }
    u16* D = WT + doff;
    const int n0 = blockIdx.x * 32, k0 = blockIdx.y * 32;
    const int c = threadIdx.x & 31, r0 = threadIdx.x >> 5;
    #pragma unroll
    for (int p = 0; p < 4; ++p)
        tile[r0 + 8*p][c] = f2bf(src[(long long)(k0 + r0 + 8*p) * HID + n0 + c]);
    __syncthreads();
    #pragma unroll
    for (int p = 0; p < 4; ++p)
        D[(long long)(n0 + r0 + 8*p) * HID + k0 + c] = tile[c][r0 + 8*p];
}

// ---- pack qkv biases: [L][3*768] ---------------------------------------
__global__ void pack_bias_all(const float* __restrict__ bq,
                              const float* __restrict__ bk,
                              const float* __restrict__ bv,
                              float* __restrict__ dst)
{
    const int part = blockIdx.x, l = blockIdx.y, h = threadIdx.x;
    const float* src = part == 0 ? bq : (part == 1 ? bk : bv);
    dst[((long long)l*3 + part) * HID + h] = src[(long long)l*HID + h];
}

// ---- big MFMA GEMM: BM=BN=128, BK=32, 4 waves, row-major + XOR swizzle --
// (r10-verified: conflict-free, coalesced, 1070 us config)
template<bool XISM, bool VSPLIT>
__global__ __launch_bounds__(256) void gemm_big(
    const u16* __restrict__ A, const u16* __restrict__ B,
    u16* __restrict__ Cp, int ldc, int N, int K,
    const float* __restrict__ bias, u16* __restrict__ vt)
{
    __shared__ u16 As[2][128 * 32];   // 2 x 8 KB
    __shared__ u16 Bs[2][128 * 32];
    const int m0 = (XISM ? blockIdx.x : blockIdx.y) * 128;
    const int n0 = (XISM ? blockIdx.y : blockIdx.x) * 128;
    const int t = threadIdx.x, w = t >> 6, l = t & 63;
    const int lrow = l >> 2;                        // row within 16-row seg
    const int wm = (w >> 1) * 64, wn = (w & 1) * 64;

    f32x4 acc[4][4];
    #pragma unroll
    for (int mi = 0; mi < 4; ++mi)
        #pragma unroll
        for (int ni = 0; ni < 4; ++ni) acc[mi][ni] = (f32x4){0.f,0.f,0.f,0.f};

    auto stage = [&](int buf, int kt) {
        #pragma unroll
        for (int r = 0; r < 2; ++r) {
            const int seg = w * 2 + r;
            const int row = seg * 16 + lrow;
            const int gslot = (l & 3) ^ ((row >> 1) & 3);
            async16(&As[buf][seg * 512],
                    A + (long long)(m0 + row) * K + kt + gslot * 8);
        }
        #pragma unroll
        for (int r = 0; r < 2; ++r) {
            const int seg = w * 2 + r;
            const int row = seg * 16 + lrow;
            const int gslot = (l & 3) ^ ((row >> 1) & 3);
            int gr = n0 + row; gr = gr < N ? gr : N - 1;
            async16(&Bs[buf][seg * 512],
                    B + (long long)gr * K + kt + gslot * 8);
        }
    };
    const int fr = l & 15, fk = l >> 4;             // fragment row, k-slot
    auto compute = [&](int cur) {
        bf16x8 af[4], bfr[4];
        #pragma unroll
        for (int mi = 0; mi < 4; ++mi) {
            const int row = wm + mi*16 + fr;
            af[mi] = *(const bf16x8*)
                &As[cur][row * 32 + ((fk ^ ((row >> 1) & 3)) << 3)];
        }
        #pragma unroll
        for (int ni = 0; ni < 4; ++ni) {
            const int row = wn + ni*16 + fr;
            bfr[ni] = *(const bf16x8*)
                &Bs[cur][row * 32 + ((fk ^ ((row >> 1) & 3)) << 3)];
        }
        #pragma unroll
        for (int mi = 0; mi < 4; ++mi)
            #pragma unroll
            for (int ni = 0; ni < 4; ++ni)
                acc[mi][ni] = __builtin_amdgcn_mfma_f32_16x16x32_bf16(
                    af[mi], bfr[ni], acc[mi][ni], 0, 0, 0);
    };

    const int NS = K >> 5;                          // 24 tiles at K=768
    stage(0, 0);
    for (int tt = 0; tt < NS; ++tt) {
        if (tt + 1 < NS) {
            stage((tt + 1) & 1, (tt + 1) << 5);
            asm volatile("s_waitcnt vmcnt(4)\n\ts_barrier" ::: "memory");
        } else {
            asm volatile("s_waitcnt vmcnt(0)\n\ts_barrier" ::: "memory");
        }
        compute(tt & 1);
        asm volatile("s_barrier" ::: "memory");
    }

    const int fq = l >> 4;
    #pragma unroll
    for (int ni = 0; ni < 4; ++ni) {
        const int col = n0 + wn + ni*16 + fr;
        if (col >= N) continue;
        const float bv = bias ? bias[col] : 0.f;
        #pragma unroll
        for (int mi = 0; mi < 4; ++mi) {
            const int row0 = m0 + wm + mi*16 + fq*4;
            if constexpr (VSPLIT) {
                if (col < 1536) {
                    #pragma unroll
                    for (int v = 0; v < 4; ++v)
                        Cp[(long long)(row0 + v) * ldc + col] =
                            f2bf(acc[mi][ni][v] + bv);
                } else {
                    const int b9 = row0 >> 9, s9 = row0 & 511;
                    u16x4 pk;
                    #pragma unroll
                    for (int v = 0; v < 4; ++v)
                        pk[v] = f2bf(acc[mi][ni][v] + bv);
                    *(u16x4*)&vt[((long long)b9 * HID + (col - 1536)) * SEQ + s9] = pk;
                }
            } else {
                #pragma unroll
                for (int v = 0; v < 4; ++v)
                    Cp[(long long)(row0 + v) * ldc + col] =
                        f2bf(acc[mi][ni][v] + bv);
            }
        }
    }
}

// ---- mid MFMA GEMM: BM=128, BN=64, BK=64, 4 waves (2M x 2N) -------------
// Staging/swizzle identical to the r5/r6-verified gemm_small pattern
// (row stride 64 u16; stage lane fetches pre-swizzled slot (l&7)^srow,
// dest linear; read phys slot = logical ^ (fr&7)). 48 KB LDS -> 3 blk/CU.
// 6 loads/thread/tile -> counted vmcnt(6).
template<bool RELU, bool OUT_BF16>
__global__ __launch_bounds__(256) void gemm_mid(
    const u16* __restrict__ A, int lda, long long sA,
    const u16* __restrict__ B, int ldb, long long sB,
    void* __restrict__ Cp, int ldc, long long sC,
    int N, int K, const float* __restrict__ bias, float alpha)
{
    __shared__ u16 As[2][128 * 64];   // 2 x 16 KB
    __shared__ u16 Bs[2][64 * 64];    // 2 x 8 KB
    const int bz = blockIdx.z;
    const int n0 = blockIdx.x * 64;
    const int m0 = blockIdx.y * 128;
    const int t = threadIdx.x, w = t >> 6, l = t & 63;
    const int srow = l >> 3;                  // row within 8-row seg
    const int skof = ((l & 7) ^ srow) * 8;    // pre-swizzled global k-slot
    const int wm = (w >> 1) * 64, wn = (w & 1) * 32;
    A += sA * bz; B += sB * bz;

    f32x4 acc[4][2];
    #pragma unroll
    for (int mi = 0; mi < 4; ++mi)
        #pragma unroll
        for (int ni = 0; ni < 2; ++ni) acc[mi][ni] = (f32x4){0.f,0.f,0.f,0.f};

    auto stage = [&](int buf, int k0) {
        #pragma unroll
        for (int r = 0; r < 4; ++r) {
            const int seg = w * 4 + r;            // 0..15 (128 rows)
            const int row = seg * 8 + srow;
            async16(&As[buf][seg * 512],
                    A + (long long)(m0 + row) * lda + (k0 + skof));
        }
        #pragma unroll
        for (int r = 0; r < 2; ++r) {
            const int seg = w * 2 + r;            // 0..7 (64 rows)
            const int row = seg * 8 + srow;
            async16(&Bs[buf][seg * 512],
                    B + (long long)(n0 + row) * ldb + (k0 + skof));
        }
    };
    const int fr = l & 15, fkb = l >> 4;      // logical slot base 0..3
    auto compute = [&](int cur) {
        #pragma unroll
        for (int ks = 0; ks < 2; ++ks) {
            const int ps = ((ks * 4 + fkb) ^ (fr & 7)) * 8;
            bf16x8 af[4], bfv[2];
            #pragma unroll
            for (int mi = 0; mi < 4; ++mi)
                af[mi] = *(const bf16x8*)&As[cur][(wm + mi*16 + fr) * 64 + ps];
            #pragma unroll
            for (int ni = 0; ni < 2; ++ni)
                bfv[ni] = *(const bf16x8*)&Bs[cur][(wn + ni*16 + fr) * 64 + ps];
            #pragma unroll
            for (int mi = 0; mi < 4; ++mi)
                #pragma unroll
                for (int ni = 0; ni < 2; ++ni)
                    acc[mi][ni] = __builtin_amdgcn_mfma_f32_16x16x32_bf16(
                        af[mi], bfv[ni], acc[mi][ni], 0, 0, 0);
        }
    };

    const int NS = K >> 6;                    // 12 (K=768) or 8 (K=512)
    stage(0, 0);
    for (int tt = 0; tt < NS; ++tt) {
        if (tt + 1 < NS) {
            stage((tt + 1) & 1, (tt + 1) << 6);
            asm volatile("s_waitcnt vmcnt(6)\n\ts_barrier" ::: "memory");
        } else {
            asm volatile("s_waitcnt vmcnt(0)\n\ts_barrier" ::: "memory");
        }
        compute(tt & 1);
        asm volatile("s_barrier" ::: "memory");
    }

    float* Cf = (float*)Cp + sC * bz;
    u16*   Ch = (u16*)Cp + sC * bz;
    const int fq = l >> 4;
    #pragma unroll
    for (int ni = 0; ni < 2; ++ni) {
        const int col = n0 + wn + ni*16 + fr;
        const float bv = bias ? bias[col] : 0.f;
        #pragma unroll
        for (int mi = 0; mi < 4; ++mi) {
            const int row0 = m0 + wm + mi*16 + fq*4;
            #pragma unroll
            for (int v = 0; v < 4; ++v) {
                float val = alpha * acc[mi][ni][v] + bv;
                if (RELU) val = fmaxf(val, 0.f);
                if (OUT_BF16) Ch[(long long)(row0 + v) * ldc + col] = f2bf(val);
                else          Cf[(long long)(row0 + v) * ldc + col] = val;
            }
        }
    }
}

// ---- fallback logits GEMM (fp32 B converted in-flight) -> bf16 out ------
__global__ __launch_bounds__(256) void gemm_conv(
    const u16* __restrict__ A, const float* __restrict__ Bf,
    u16* __restrict__ C)  // C = (u16*)out + VOC, ldc 2*VOC
{
    __shared__ u16 As[128 * 32];
    __shared__ u16 Bs[128 * 32];
    const int m0 = blockIdx.x * 128;
    const int n0 = blockIdx.y * 128;
    const int t = threadIdx.x, w = t >> 6, l = t & 63;
    const int lrow = l >> 2, lk8 = (l & 3) * 8;
    const int wm = (w >> 1) * 64, wn = (w & 1) * 64;
    f32x4 acc[4][4];
    #pragma unroll
    for (int mi = 0; mi < 4; ++mi)
        #pragma unroll
        for (int ni = 0; ni < 4; ++ni) acc[mi][ni] = (f32x4){0.f,0.f,0.f,0.f};

    for (int k0 = 0; k0 < HID; k0 += 32) {
        #pragma unroll
        for (int r = 0; r < 2; ++r) {
            const int seg = w * 2 + r;
            async16(&As[seg * 512],
                    A + (long long)(m0 + seg*16 + lrow) * HID + (k0 + lk8));
        }
        #pragma unroll
        for (int r = 0; r < 2; ++r) {
            const int flat = r * 2048 + t * 8;
            int row = n0 + (flat >> 5);
            row = row < VOC ? row : VOC - 1;
            const float* g = Bf + (long long)row * HID + (k0 + (flat & 31));
            const float4 v0 = *(const float4*)g;
            const float4 v1 = *(const float4*)(g + 4);
            bf16x8 hv;
            hv[0]=(short)f2bf(v0.x); hv[1]=(short)f2bf(v0.y);
            hv[2]=(short)f2bf(v0.z); hv[3]=(short)f2bf(v0.w);
            hv[4]=(short)f2bf(v1.x); hv[5]=(short)f2bf(v1.y);
            hv[6]=(short)f2bf(v1.z); hv[7]=(short)f2bf(v1.w);
            *(bf16x8*)&Bs[flat] = hv;
        }
        __syncthreads();
        const int fr = l & 15, fk = (l >> 4) * 8;
        bf16x8 af[4], bfr[4];
        #pragma unroll
        for (int mi = 0; mi < 4; ++mi)
            af[mi] = *(const bf16x8*)&As[(wm + mi*16 + fr) * 32 + fk];
        #pragma unroll
        for (int ni = 0; ni < 4; ++ni)
            bfr[ni] = *(const bf16x8*)&Bs[(wn + ni*16 + fr) * 32 + fk];
        #pragma unroll
        for (int mi = 0; mi < 4; ++mi)
            #pragma unroll
            for (int ni = 0; ni < 4; ++ni)
                acc[mi][ni] = __builtin_amdgcn_mfma_f32_16x16x32_bf16(
                    af[mi], bfr[ni], acc[mi][ni], 0, 0, 0);
        __syncthreads();
    }
    const int fr = l & 15, fq = l >> 4;
    #pragma unroll
    for (int ni = 0; ni < 4; ++ni) {
        const int col = n0 + wn + ni*16 + fr;
        if (col >= VOC) continue;
        #pragma unroll
        for (int mi = 0; mi < 4; ++mi) {
            const int row0 = m0 + wm + mi*16 + fq*4;
            #pragma unroll
            for (int v = 0; v < 4; ++v)
                C[(long long)(row0 + v) * (2*VOC) + col] = f2bf(acc[mi][ni][v]);
        }
    }
}

// ---- masked softmax over QUERY axis (dim=1): fp32 in, bf16 out ----------
__global__ __launch_bounds__(256) void softmax_q_kernel(
    const float* __restrict__ sc, u16* __restrict__ att,
    const int* __restrict__ lengths)
{
    const int b  = blockIdx.x;
    const int k0 = blockIdx.y * 16;
    const int tx = threadIdx.x & 15;
    const int ty = threadIdx.x >> 4;
    const int c  = k0 + tx;
    const int len = lengths[b];
    const float* base  = sc  + (long long)b * SEQ * SEQ;
    u16*         obase = att + (long long)b * SEQ * SEQ;
    const bool cvalid = (c < len);

    float vals[32];
    float m = -3.0e38f, ssum = 0.f;
    #pragma unroll
    for (int i = 0; i < 32; ++i) {
        const int q = ty + 16 * i;
        float xv = -3.0e38f;
        if (cvalid && c <= q && q < len)
            xv = base[(long long)q * SEQ + c];
        vals[i] = xv;
        if (xv > m) { ssum = ssum * __expf(m - xv) + 1.f; m = xv; }
        else if (xv > -3.0e38f) { ssum += __expf(xv - m); }
    }
    __shared__ float ms[16][17], ss[16][17];
    ms[ty][tx] = m; ss[ty][tx] = ssum;
    __syncthreads();
    if (ty == 0) {
        float M = ms[0][tx];
        #pragma unroll
        for (int r = 1; r < 16; ++r) M = fmaxf(M, ms[r][tx]);
        float Sx = 0.f;
        #pragma unroll
        for (int r = 0; r < 16; ++r) Sx += ss[r][tx] * __expf(ms[r][tx] - M);
        ms[0][tx] = M; ss[0][tx] = Sx;
    }
    __syncthreads();
    const float M   = ms[0][tx];
    const float den = ss[0][tx];
    const float inv = (den > 0.f) ? 1.f / den : 0.f;
    #pragma unroll
    for (int i = 0; i < 32; ++i) {
        const int q = ty + 16 * i;
        obase[(long long)q * SEQ + c] = f2bf(__expf(vals[i] - M) * inv);
    }
}

// ---- fused residual-add + LayerNorm: wave-per-row, float4, no barriers --
__global__ __launch_bounds__(256) void ln_add_kernel(
    const float* __restrict__ Xa, const float* __restrict__ Xb,
    float* __restrict__ O, u16* __restrict__ Oh,
    const float* __restrict__ g, const float* __restrict__ be)
{
    const int row = blockIdx.x * 4 + (threadIdx.x >> 6);
    const int l = threadIdx.x & 63;
    const long long base = (long long)row * HID;
    float x[12];
    #pragma unroll
    for (int c = 0; c < 3; ++c) {
        const int off = c * 256 + l * 4;
        const float4 a = *(const float4*)&Xa[base + off];
        const float4 b = *(const float4*)&Xb[base + off];
        x[c*4+0] = a.x + b.x; x[c*4+1] = a.y + b.y;
        x[c*4+2] = a.z + b.z; x[c*4+3] = a.w + b.w;
    }
    float s = 0.f;
    #pragma unroll
    for (int i = 0; i < 12; ++i) s += x[i];
    #pragma unroll
    for (int o = 32; o; o >>= 1) s += __shfl_xor(s, o, 64);
    const float mean = s * (1.f / HID);
    float v = 0.f;
    #pragma unroll
    for (int i = 0; i < 12; ++i) { const float d = x[i] - mean; v += d * d; }
    #pragma unroll
    for (int o = 32; o; o >>= 1) v += __shfl_xor(v, o, 64);
    const float rs = rsqrtf(v * (1.f / HID) + EPSLN);
    #pragma unroll
    for (int c = 0; c < 3; ++c) {
        const int off = c * 256 + l * 4;
        const float4 gg = *(const float4*)&g[off];
        const float4 bb = *(const float4*)&be[off];
        float4 y;
        y.x = (x[c*4+0] - mean) * rs * gg.x + bb.x;
        y.y = (x[c*4+1] - mean) * rs * gg.y + bb.y;
        y.z = (x[c*4+2] - mean) * rs * gg.z + bb.z;
        y.w = (x[c*4+3] - mean) * rs * gg.w + bb.w;
        *(float4*)&O[base + off] = y;
        u16x4 p;
        p[0] = f2bf(y.x); p[1] = f2bf(y.y); p[2] = f2bf(y.z); p[3] = f2bf(y.w);
        *(u16x4*)&Oh[base + off] = p;
    }
}

// ---- vocab softmax: bf16 logits in (row-local upper half), fp32 out -----
__global__ __launch_bounds__(256) void softmax_v_kernel(float* __restrict__ out)
{
    __shared__ float row[VOC];            // 40 KB
    __shared__ float rm[4], rs_[4];
    const long long obase = (long long)blockIdx.x * VOC;
    const u16* lg = (const u16*)out + 2 * obase + VOC;  // bf16 logits row
    const int t = threadIdx.x;
    float m = -3.0e38f, s = 0.f;
    for (int i = t * 8; i < VOC; i += 2048) {
        const u16x8 h8 = *(const u16x8*)&lg[i];
        #pragma unroll
        for (int j = 0; j < 8; ++j) {
            const float xv = bf2f(h8[j]);
            row[i + j] = xv;
            const float d = xv - m;
            if (d > 0.f) { s = s * __expf(-d) + 1.f; m = xv; }
            else         { s += __expf(d); }
        }
    }
    #pragma unroll
    for (int o = 32; o; o >>= 1) {
        const float om = __shfl_down(m, o, 64), os = __shfl_down(s, o, 64);
        const float M = fmaxf(m, om);
        s = s * __expf(m - M) + os * __expf(om - M);
        m = M;
    }
    if ((t & 63) == 0) { rm[t >> 6] = m; rs_[t >> 6] = s; }
    __syncthreads();
    const float M = fmaxf(fmaxf(rm[0], rm[1]), fmaxf(rm[2], rm[3]));
    const float S = rs_[0]*__expf(rm[0]-M) + rs_[1]*__expf(rm[1]-M)
                  + rs_[2]*__expf(rm[2]-M) + rs_[3]*__expf(rm[3]-M);
    const float inv = 1.f / S;
    for (int i = t * 4; i < VOC; i += 1024) {
        float4 v = *(const float4*)&row[i];
        v.x = __expf(v.x - M) * inv;
        v.y = __expf(v.y - M) * inv;
        v.z = __expf(v.z - M) * inv;
        v.w = __expf(v.w - M) * inv;
        *(float4*)&out[obase + i] = v;
    }
}

// ---- host-side orchestration -------------------------------------------
extern "C" void kernel_launch(void* const* d_in, const int* in_sizes, int n_in,
                              void* d_out, int out_size, void* d_ws, size_t ws_size,
                              hipStream_t stream)
{
    const int*   x    = (const int*)  d_in[0];
    const int*   lens = (const int*)  d_in[1];
    const float* emb  = (const float*)d_in[2];
    const float* Wq   = (const float*)d_in[3];
    const float* bq   = (const float*)d_in[4];
    const float* Wk   = (const float*)d_in[5];
    const float* bk   = (const float*)d_in[6];
    const float* Wv   = (const float*)d_in[7];
    const float* bv   = (const float*)d_in[8];
    const float* W1   = (const float*)d_in[9];
    const float* b1   = (const float*)d_in[10];
    const float* W2   = (const float*)d_in[11];
    const float* b2   = (const float*)d_in[12];
    const float* g1   = (const float*)d_in[13];
    const float* be1  = (const float*)d_in[14];
    const float* g2   = (const float*)d_in[15];
    const float* be2  = (const float*)d_in[16];
    const float* fcw  = (const float*)d_in[17];
    const float* fcb  = (const float*)d_in[18];

    float* out = (float*)d_out;
    float* Zb     = out;
    float* O1f    = Zb + NH;
    float* M2f    = O1f + NH;
    float* SCORES = M2f + NH;
    float* BQKV   = SCORES + SS8;                   // [L][2304]
    u16* ub   = (u16*)(BQKV + (long long)LAYERS * 2304);
    u16* Zbh  = ub;  ub += NH;
    u16* QKVh = ub;  ub += (long long)NROWS * 1536; // Q|K, ldc 1536
    u16* ATTB = ub;  ub += SS8;
    u16* Vt   = ub;  ub += NH;                      // [B][H][S]
    u16* O1h  = ub;  ub += NH;
    u16* M1h  = ub;  ub += NH;
    u16* WT   = ub;  ub += 41LL * WSZ;

    u16* ZFh = (u16*)d_ws;
    u16* EH  = ZFh + NH;
    const bool ehpath = ws_size >= (size_t)((NH + (long long)VOC * HID) * 2);
    u16* LOGH = (u16*)out + VOC;                    // bf16 logits, ldc 2*VOC

    const float scale = 1.0f / sqrtf((float)HID);
    const dim3 blk(256);

    embed_kernel<<<NROWS, blk, 0, stream>>>(x, emb, Zb, Zbh);
    transp_all<<<dim3(24, 24, 41), blk, 0, stream>>>(Wq, Wk, Wv, W1, W2, fcw, WT);
    pack_bias_all<<<dim3(3, LAYERS), dim3(768), 0, stream>>>(bq, bk, bv, BQKV);
    if (ehpath) convert_emb<<<7500, blk, 0, stream>>>(emb, EH);

    for (int l = 0; l < LAYERS; ++l) {
        const u16* wl = WT + (long long)l * 5 * WSZ;

        // qkv: Q,K -> QKVh[4096][1536]; V -> Vt transposed.
        gemm_big<false, true><<<dim3(18, 32), blk, 0, stream>>>(
            Zbh, wl, QKVh, 1536, 2304, HID,
            BQKV + (long long)l * 2304, Vt);

        // scores = scale * Q @ K^T   (grid 8x4x8 = 256 blocks)
        gemm_mid<false, false><<<dim3(8, 4, BATCH), blk, 0, stream>>>(
            QKVh, 1536, (long long)SEQ * 1536,
            QKVh + 768, 1536, (long long)SEQ * 1536,
            SCORES, SEQ, (long long)SEQ * SEQ,
            512, HID, nullptr, scale);

        softmax_q_kernel<<<dim3(BATCH, SEQ/16), blk, 0, stream>>>(SCORES, ATTB, lens);

        // attnout = att @ V   (grid 12x4x8 = 384 blocks)
        gemm_mid<false, false><<<dim3(12, 4, BATCH), blk, 0, stream>>>(
            ATTB, SEQ, (long long)SEQ * SEQ,
            Vt, SEQ, (long long)HID * SEQ,
            O1f, HID, (long long)SEQ * HID,
            768, SEQ, nullptr, 1.0f);

        ln_add_kernel<<<NROWS/4, blk, 0, stream>>>(Zb, O1f, O1f, O1h,
                                                   g1 + l*HID, be1 + l*HID);
        // FFN (grid 12x32 = 384 blocks each)
        gemm_mid<true, true><<<dim3(12, 32), blk, 0, stream>>>(
            O1h, HID, 0, wl + 3*WSZ, HID, 0, M1h, HID, 0,
            768, HID, b1 + l*HID, 1.0f);
        gemm_mid<false, false><<<dim3(12, 32), blk, 0, stream>>>(
            M1h, HID, 0, wl + 4*WSZ, HID, 0, M2f, HID, 0,
            768, HID, b2 + l*HID, 1.0f);
        ln_add_kernel<<<NROWS/4, blk, 0, stream>>>(M2f, O1f, Zb, Zbh,
                                                   g2 + l*HID, be2 + l*HID);
    }

    // fc: zf = z @ fc_w + fc_b -> bf16 in d_ws  (grid 12x32 = 384)
    gemm_mid<false, true><<<dim3(12, 32), blk, 0, stream>>>(
        Zbh, HID, 0, WT + 40LL*WSZ, HID, 0, ZFh, HID, 0,
        768, HID, fcb, 1.0f);

    // logits = zf @ emb^T -> bf16, row-local upper half of d_out.
    // XISM: consecutive blocks share the emb B-panel (L2 reuse).
    if (ehpath) {
        gemm_big<true, false><<<dim3(32, 79), blk, 0, stream>>>(
            ZFh, EH, LOGH, 2*VOC, VOC, HID, nullptr, nullptr);
    } else {
        gemm_conv<<<dim3(32, 79), blk, 0, stream>>>(ZFh, emb, LOGH);
    }

    softmax_v_kernel<<<NROWS, blk, 0, stream>>>(out);
}

// Round 13
// 1072.612 us; speedup vs baseline: 1.1655x; 1.0238x over previous
//
#include <hip/hip_runtime.h>
#include <math.h>

typedef unsigned int   u32;
typedef unsigned short u16;
typedef __attribute__((ext_vector_type(8))) short bf16x8;
typedef __attribute__((ext_vector_type(4))) float f32x4;
typedef __attribute__((ext_vector_type(4))) unsigned short u16x4;
typedef __attribute__((ext_vector_type(8))) unsigned short u16x8;

#define HID   768
#define SEQ   512
#define BATCH 8
#define LAYERS 8
#define VOC   10000
#define NROWS (BATCH*SEQ)             // 4096
#define NH    ((long long)NROWS*HID)  // 3,145,728
#define SS8   ((long long)BATCH*SEQ*SEQ)
#define EPSLN 1e-5f
#define WSZ   ((long long)HID*HID)    // 589824

__device__ __forceinline__ u16 f2bf(float f) {
    u32 u = __builtin_bit_cast(u32, f);
    return (u16)((u + 0x7fffu + ((u >> 16) & 1u)) >> 16);
}
__device__ __forceinline__ float bf2f(u16 h) {
    return __builtin_bit_cast(float, (u32)h << 16);
}

__device__ __forceinline__ void async16(u16* lds, const u16* g) {
    __builtin_amdgcn_global_load_lds(
        (const __attribute__((address_space(1))) u32*)g,
        (__attribute__((address_space(3))) u32*)lds, 16, 0, 0);
}

// ---- embedding + positional encoding (fp32 + bf16 shadow) ---------------
__global__ __launch_bounds__(256) void embed_kernel(
    const int* __restrict__ x, const float* __restrict__ emb,
    float* __restrict__ Z, u16* __restrict__ Zh)
{
    const int row = blockIdx.x;
    const int s   = row & (SEQ - 1);
    const int tok = x[row];
    const long long base  = (long long)row * HID;
    const long long ebase = (long long)tok * HID;
    const float coef = -0.0239852613853544f;   // -2*ln(10000)/768
    #pragma unroll
    for (int j = 0; j < 3; ++j) {
        const int h = threadIdx.x + 256 * j;
        const int i = h >> 1;
        const float ang = (float)s * expf((float)i * coef);
        const float pe  = (h & 1) ? cosf(ang) : sinf(ang);
        const float v = emb[ebase + h] + pe;
        Z[base + h]  = v;
        Zh[base + h] = f2bf(v);
    }
}

// ---- emb fp32 -> bf16, vectorized --------------------------------------
__global__ __launch_bounds__(256) void convert_emb(
    const float* __restrict__ e, u16* __restrict__ eh)
{
    const long long i = ((long long)blockIdx.x * 256 + threadIdx.x) * 4;
    const float4 v = *(const float4*)&e[i];
    u16x4 p;
    p[0] = f2bf(v.x); p[1] = f2bf(v.y); p[2] = f2bf(v.z); p[3] = f2bf(v.w);
    *(u16x4*)&eh[i] = p;
}

// ---- all-weights transpose+convert: fp32 [K,N] -> bf16 [N,K] ------------
__global__ __launch_bounds__(256) void transp_all(
    const float* __restrict__ Wq, const float* __restrict__ Wk,
    const float* __restrict__ Wv, const float* __restrict__ W1,
    const float* __restrict__ W2, const float* __restrict__ fcw,
    u16* __restrict__ WT)
{
    __shared__ u16 tile[32][34];
    const int z = blockIdx.z;
    const float* src;
    long long doff;
    if (z < 40) {
        const int lyr = z / 5, idx = z % 5;
        const float* bases[5] = {Wq, Wk, Wv, W1, W2};
        src  = bases[idx] + (long long)lyr * WSZ;
        doff = ((long long)lyr * 5 + idx) * WSZ;
    } else {
        src = fcw; doff = 40LL * WSZ;
    }
    u16* D = WT + doff;
    const int n0 = blockIdx.x * 32, k0 = blockIdx.y * 32;
    const int c = threadIdx.x & 31, r0 = threadIdx.x >> 5;
    #pragma unroll
    for (int p = 0; p < 4; ++p)
        tile[r0 + 8*p][c] = f2bf(src[(long long)(k0 + r0 + 8*p) * HID + n0 + c]);
    __syncthreads();
    #pragma unroll
    for (int p = 0; p < 4; ++p)
        D[(long long)(n0 + r0 + 8*p) * HID + k0 + c] = tile[c][r0 + 8*p];
}

// ---- pack qkv biases: [L][3*768] ---------------------------------------
__global__ void pack_bias_all(const float* __restrict__ bq,
                              const float* __restrict__ bk,
                              const float* __restrict__ bv,
                              float* __restrict__ dst)
{
    const int part = blockIdx.x, l = blockIdx.y, h = threadIdx.x;
    const float* src = part == 0 ? bq : (part == 1 ? bk : bv);
    dst[((long long)l*3 + part) * HID + h] = src[(long long)l*HID + h];
}

// ---- big MFMA GEMM: BM=BN=128, BK=32, 4 waves, row-major + XOR swizzle --
// (r10-verified core.) XCDSWZ: 1-D grid, fid&7 selects XCD class; all
// blocks sharing a `by` panel land on one XCD -> panel fetched into ONE
// L2 instead of 8 (T1). Requires gy % 8 == 0 (grid padded; OOB cols skip).
template<bool XISM, bool VSPLIT, bool XCDSWZ>
__global__ __launch_bounds__(256) void gemm_big(
    const u16* __restrict__ A, const u16* __restrict__ B,
    u16* __restrict__ Cp, int ldc, int N, int K,
    const float* __restrict__ bias, u16* __restrict__ vt, int gxdim)
{
    __shared__ u16 As[2][128 * 32];   // 2 x 8 KB
    __shared__ u16 Bs[2][128 * 32];
    int bx, by;
    if constexpr (XCDSWZ) {
        const int fid = blockIdx.x;
        const int xcd = fid & 7, j = fid >> 3;
        bx = j % gxdim;
        by = xcd + 8 * (j / gxdim);
    } else { bx = blockIdx.x; by = blockIdx.y; }
    const int m0 = (XISM ? bx : by) * 128;
    const int n0 = (XISM ? by : bx) * 128;
    const int t = threadIdx.x, w = t >> 6, l = t & 63;
    const int lrow = l >> 2;                        // row within 16-row seg
    const int wm = (w >> 1) * 64, wn = (w & 1) * 64;

    f32x4 acc[4][4];
    #pragma unroll
    for (int mi = 0; mi < 4; ++mi)
        #pragma unroll
        for (int ni = 0; ni < 4; ++ni) acc[mi][ni] = (f32x4){0.f,0.f,0.f,0.f};

    auto stage = [&](int buf, int kt) {
        #pragma unroll
        for (int r = 0; r < 2; ++r) {
            const int seg = w * 2 + r;
            const int row = seg * 16 + lrow;
            const int gslot = (l & 3) ^ ((row >> 1) & 3);
            async16(&As[buf][seg * 512],
                    A + (long long)(m0 + row) * K + kt + gslot * 8);
        }
        #pragma unroll
        for (int r = 0; r < 2; ++r) {
            const int seg = w * 2 + r;
            const int row = seg * 16 + lrow;
            const int gslot = (l & 3) ^ ((row >> 1) & 3);
            int gr = n0 + row; gr = gr < N ? gr : N - 1;
            async16(&Bs[buf][seg * 512],
                    B + (long long)gr * K + kt + gslot * 8);
        }
    };
    const int fr = l & 15, fk = l >> 4;             // fragment row, k-slot
    auto compute = [&](int cur) {
        bf16x8 af[4], bfr[4];
        #pragma unroll
        for (int mi = 0; mi < 4; ++mi) {
            const int row = wm + mi*16 + fr;
            af[mi] = *(const bf16x8*)
                &As[cur][row * 32 + ((fk ^ ((row >> 1) & 3)) << 3)];
        }
        #pragma unroll
        for (int ni = 0; ni < 4; ++ni) {
            const int row = wn + ni*16 + fr;
            bfr[ni] = *(const bf16x8*)
                &Bs[cur][row * 32 + ((fk ^ ((row >> 1) & 3)) << 3)];
        }
        #pragma unroll
        for (int mi = 0; mi < 4; ++mi)
            #pragma unroll
            for (int ni = 0; ni < 4; ++ni)
                acc[mi][ni] = __builtin_amdgcn_mfma_f32_16x16x32_bf16(
                    af[mi], bfr[ni], acc[mi][ni], 0, 0, 0);
    };

    const int NS = K >> 5;                          // 24 tiles at K=768
    stage(0, 0);
    for (int tt = 0; tt < NS; ++tt) {
        if (tt + 1 < NS) {
            stage((tt + 1) & 1, (tt + 1) << 5);
            asm volatile("s_waitcnt vmcnt(4)\n\ts_barrier" ::: "memory");
        } else {
            asm volatile("s_waitcnt vmcnt(0)\n\ts_barrier" ::: "memory");
        }
        compute(tt & 1);
        asm volatile("s_barrier" ::: "memory");
    }

    const int fq = l >> 4;
    #pragma unroll
    for (int ni = 0; ni < 4; ++ni) {
        const int col = n0 + wn + ni*16 + fr;
        if (col >= N) continue;
        const float bv = bias ? bias[col] : 0.f;
        #pragma unroll
        for (int mi = 0; mi < 4; ++mi) {
            const int row0 = m0 + wm + mi*16 + fq*4;
            if constexpr (VSPLIT) {
                if (col < 1536) {
                    #pragma unroll
                    for (int v = 0; v < 4; ++v)
                        Cp[(long long)(row0 + v) * ldc + col] =
                            f2bf(acc[mi][ni][v] + bv);
                } else {
                    const int b9 = row0 >> 9, s9 = row0 & 511;
                    u16x4 pk;
                    #pragma unroll
                    for (int v = 0; v < 4; ++v)
                        pk[v] = f2bf(acc[mi][ni][v] + bv);
                    *(u16x4*)&vt[((long long)b9 * HID + (col - 1536)) * SEQ + s9] = pk;
                }
            } else {
                #pragma unroll
                for (int v = 0; v < 4; ++v)
                    Cp[(long long)(row0 + v) * ldc + col] =
                        f2bf(acc[mi][ni][v] + bv);
            }
        }
    }
}

// ---- small MFMA GEMM: BM=BN=64, BK=64, 2 waves, XOR-swizzled LDS --------
// (r5/r6/r10-verified)
template<bool RELU, bool OUT_BF16>
__global__ __launch_bounds__(128) void gemm_small(
    const u16* __restrict__ A, int lda, long long sA,
    const u16* __restrict__ B, int ldb, long long sB,
    void* __restrict__ Cp, int ldc, long long sC,
    int N, int K, const float* __restrict__ bias, float alpha)
{
    __shared__ u16 As[2][64 * 64];
    __shared__ u16 Bs[2][64 * 64];
    const int bz = blockIdx.z;
    const int n0 = blockIdx.x * 64;
    const int m0 = blockIdx.y * 64;
    const int t = threadIdx.x, w = t >> 6, l = t & 63;
    const int srow = l >> 3;                  // row within 8-row seg
    const int skof = ((l & 7) ^ srow) * 8;    // pre-swizzled global k-slot
    const int wm = w * 32;
    A += sA * bz; B += sB * bz;

    f32x4 acc[2][4];
    #pragma unroll
    for (int mi = 0; mi < 2; ++mi)
        #pragma unroll
        for (int ni = 0; ni < 4; ++ni) acc[mi][ni] = (f32x4){0.f,0.f,0.f,0.f};

    auto stage = [&](int buf, int k0) {
        #pragma unroll
        for (int r = 0; r < 4; ++r) {
            const int seg = w * 4 + r;
            const int row = seg * 8 + srow;
            async16(&As[buf][seg * 512],
                    A + (long long)(m0 + row) * lda + (k0 + skof));
        }
        #pragma unroll
        for (int r = 0; r < 4; ++r) {
            const int seg = w * 4 + r;
            const int row = seg * 8 + srow;
            async16(&Bs[buf][seg * 512],
                    B + (long long)(n0 + row) * ldb + (k0 + skof));
        }
    };
    const int fr = l & 15, fkb = l >> 4;      // logical slot base 0..3
    auto compute = [&](int cur) {
        #pragma unroll
        for (int ks = 0; ks < 2; ++ks) {
            const int ps = ((ks * 4 + fkb) ^ (fr & 7)) * 8;
            bf16x8 af[2], bfv[4];
            #pragma unroll
            for (int mi = 0; mi < 2; ++mi)
                af[mi] = *(const bf16x8*)&As[cur][(wm + mi*16 + fr) * 64 + ps];
            #pragma unroll
            for (int ni = 0; ni < 4; ++ni)
                bfv[ni] = *(const bf16x8*)&Bs[cur][(ni*16 + fr) * 64 + ps];
            #pragma unroll
            for (int mi = 0; mi < 2; ++mi)
                #pragma unroll
                for (int ni = 0; ni < 4; ++ni)
                    acc[mi][ni] = __builtin_amdgcn_mfma_f32_16x16x32_bf16(
                        af[mi], bfv[ni], acc[mi][ni], 0, 0, 0);
        }
    };

    const int NS = K >> 6;                    // 12 (K=768) or 8 (K=512)
    stage(0, 0);
    for (int tt = 0; tt < NS; ++tt) {
        if (tt + 1 < NS) {
            stage((tt + 1) & 1, (tt + 1) << 6);
            asm volatile("s_waitcnt vmcnt(8)\n\ts_barrier" ::: "memory");
        } else {
            asm volatile("s_waitcnt vmcnt(0)\n\ts_barrier" ::: "memory");
        }
        compute(tt & 1);
        asm volatile("s_barrier" ::: "memory");
    }

    float* Cf = (float*)Cp + sC * bz;
    u16*   Ch = (u16*)Cp + sC * bz;
    const int fq = l >> 4;
    #pragma unroll
    for (int ni = 0; ni < 4; ++ni) {
        const int col = n0 + ni*16 + fr;
        const float bv = bias ? bias[col] : 0.f;
        #pragma unroll
        for (int mi = 0; mi < 2; ++mi) {
            const int row0 = m0 + wm + mi*16 + fq*4;
            #pragma unroll
            for (int v = 0; v < 4; ++v) {
                float val = alpha * acc[mi][ni][v] + bv;
                if (RELU) val = fmaxf(val, 0.f);
                if (OUT_BF16) Ch[(long long)(row0 + v) * ldc + col] = f2bf(val);
                else          Cf[(long long)(row0 + v) * ldc + col] = val;
            }
        }
    }
}

// ---- fallback logits GEMM (fp32 B converted in-flight) -> bf16 out ------
__global__ __launch_bounds__(256) void gemm_conv(
    const u16* __restrict__ A, const float* __restrict__ Bf,
    u16* __restrict__ C)  // C = (u16*)out + VOC, ldc 2*VOC
{
    __shared__ u16 As[128 * 32];
    __shared__ u16 Bs[128 * 32];
    const int m0 = blockIdx.x * 128;
    const int n0 = blockIdx.y * 128;
    const int t = threadIdx.x, w = t >> 6, l = t & 63;
    const int lrow = l >> 2, lk8 = (l & 3) * 8;
    const int wm = (w >> 1) * 64, wn = (w & 1) * 64;
    f32x4 acc[4][4];
    #pragma unroll
    for (int mi = 0; mi < 4; ++mi)
        #pragma unroll
        for (int ni = 0; ni < 4; ++ni) acc[mi][ni] = (f32x4){0.f,0.f,0.f,0.f};

    for (int k0 = 0; k0 < HID; k0 += 32) {
        #pragma unroll
        for (int r = 0; r < 2; ++r) {
            const int seg = w * 2 + r;
            async16(&As[seg * 512],
                    A + (long long)(m0 + seg*16 + lrow) * HID + (k0 + lk8));
        }
        #pragma unroll
        for (int r = 0; r < 2; ++r) {
            const int flat = r * 2048 + t * 8;
            int row = n0 + (flat >> 5);
            row = row < VOC ? row : VOC - 1;
            const float* g = Bf + (long long)row * HID + (k0 + (flat & 31));
            const float4 v0 = *(const float4*)g;
            const float4 v1 = *(const float4*)(g + 4);
            bf16x8 hv;
            hv[0]=(short)f2bf(v0.x); hv[1]=(short)f2bf(v0.y);
            hv[2]=(short)f2bf(v0.z); hv[3]=(short)f2bf(v0.w);
            hv[4]=(short)f2bf(v1.x); hv[5]=(short)f2bf(v1.y);
            hv[6]=(short)f2bf(v1.z); hv[7]=(short)f2bf(v1.w);
            *(bf16x8*)&Bs[flat] = hv;
        }
        __syncthreads();
        const int fr = l & 15, fk = (l >> 4) * 8;
        bf16x8 af[4], bfr[4];
        #pragma unroll
        for (int mi = 0; mi < 4; ++mi)
            af[mi] = *(const bf16x8*)&As[(wm + mi*16 + fr) * 32 + fk];
        #pragma unroll
        for (int ni = 0; ni < 4; ++ni)
            bfr[ni] = *(const bf16x8*)&Bs[(wn + ni*16 + fr) * 32 + fk];
        #pragma unroll
        for (int mi = 0; mi < 4; ++mi)
            #pragma unroll
            for (int ni = 0; ni < 4; ++ni)
                acc[mi][ni] = __builtin_amdgcn_mfma_f32_16x16x32_bf16(
                    af[mi], bfr[ni], acc[mi][ni], 0, 0, 0);
        __syncthreads();
    }
    const int fr = l & 15, fq = l >> 4;
    #pragma unroll
    for (int ni = 0; ni < 4; ++ni) {
        const int col = n0 + wn + ni*16 + fr;
        if (col >= VOC) continue;
        #pragma unroll
        for (int mi = 0; mi < 4; ++mi) {
            const int row0 = m0 + wm + mi*16 + fq*4;
            #pragma unroll
            for (int v = 0; v < 4; ++v)
                C[(long long)(row0 + v) * (2*VOC) + col] = f2bf(acc[mi][ni][v]);
        }
    }
}

// ---- masked softmax over QUERY axis (dim=1): bf16 in, bf16 out ----------
__global__ __launch_bounds__(256) void softmax_q_kernel(
    const u16* __restrict__ sc, u16* __restrict__ att,
    const int* __restrict__ lengths)
{
    const int b  = blockIdx.x;
    const int k0 = blockIdx.y * 16;
    const int tx = threadIdx.x & 15;
    const int ty = threadIdx.x >> 4;
    const int c  = k0 + tx;
    const int len = lengths[b];
    const u16* base  = sc  + (long long)b * SEQ * SEQ;
    u16*       obase = att + (long long)b * SEQ * SEQ;
    const bool cvalid = (c < len);

    float vals[32];
    float m = -3.0e38f, ssum = 0.f;
    #pragma unroll
    for (int i = 0; i < 32; ++i) {
        const int q = ty + 16 * i;
        float xv = -3.0e38f;
        if (cvalid && c <= q && q < len)
            xv = bf2f(base[(long long)q * SEQ + c]);
        vals[i] = xv;
        if (xv > m) { ssum = ssum * __expf(m - xv) + 1.f; m = xv; }
        else if (xv > -3.0e38f) { ssum += __expf(xv - m); }
    }
    __shared__ float ms[16][17], ss[16][17];
    ms[ty][tx] = m; ss[ty][tx] = ssum;
    __syncthreads();
    if (ty == 0) {
        float M = ms[0][tx];
        #pragma unroll
        for (int r = 1; r < 16; ++r) M = fmaxf(M, ms[r][tx]);
        float Sx = 0.f;
        #pragma unroll
        for (int r = 0; r < 16; ++r) Sx += ss[r][tx] * __expf(ms[r][tx] - M);
        ms[0][tx] = M; ss[0][tx] = Sx;
    }
    __syncthreads();
    const float M   = ms[0][tx];
    const float den = ss[0][tx];
    const float inv = (den > 0.f) ? 1.f / den : 0.f;
    #pragma unroll
    for (int i = 0; i < 32; ++i) {
        const int q = ty + 16 * i;
        obase[(long long)q * SEQ + c] = f2bf(__expf(vals[i] - M) * inv);
    }
}

// ---- fused residual-add + LayerNorm: wave-per-row, float4, no barriers --
__global__ __launch_bounds__(256) void ln_add_kernel(
    const float* __restrict__ Xa, const float* __restrict__ Xb,
    float* __restrict__ O, u16* __restrict__ Oh,
    const float* __restrict__ g, const float* __restrict__ be)
{
    const int row = blockIdx.x * 4 + (threadIdx.x >> 6);
    const int l = threadIdx.x & 63;
    const long long base = (long long)row * HID;
    float x[12];
    #pragma unroll
    for (int c = 0; c < 3; ++c) {
        const int off = c * 256 + l * 4;
        const float4 a = *(const float4*)&Xa[base + off];
        const float4 b = *(const float4*)&Xb[base + off];
        x[c*4+0] = a.x + b.x; x[c*4+1] = a.y + b.y;
        x[c*4+2] = a.z + b.z; x[c*4+3] = a.w + b.w;
    }
    float s = 0.f;
    #pragma unroll
    for (int i = 0; i < 12; ++i) s += x[i];
    #pragma unroll
    for (int o = 32; o; o >>= 1) s += __shfl_xor(s, o, 64);
    const float mean = s * (1.f / HID);
    float v = 0.f;
    #pragma unroll
    for (int i = 0; i < 12; ++i) { const float d = x[i] - mean; v += d * d; }
    #pragma unroll
    for (int o = 32; o; o >>= 1) v += __shfl_xor(v, o, 64);
    const float rs = rsqrtf(v * (1.f / HID) + EPSLN);
    #pragma unroll
    for (int c = 0; c < 3; ++c) {
        const int off = c * 256 + l * 4;
        const float4 gg = *(const float4*)&g[off];
        const float4 bb = *(const float4*)&be[off];
        float4 y;
        y.x = (x[c*4+0] - mean) * rs * gg.x + bb.x;
        y.y = (x[c*4+1] - mean) * rs * gg.y + bb.y;
        y.z = (x[c*4+2] - mean) * rs * gg.z + bb.z;
        y.w = (x[c*4+3] - mean) * rs * gg.w + bb.w;
        *(float4*)&O[base + off] = y;
        u16x4 p;
        p[0] = f2bf(y.x); p[1] = f2bf(y.y); p[2] = f2bf(y.z); p[3] = f2bf(y.w);
        *(u16x4*)&Oh[base + off] = p;
    }
}

// ---- vocab softmax: bf16 logits in (row-local upper half), fp32 out -----
__global__ __launch_bounds__(256) void softmax_v_kernel(float* __restrict__ out)
{
    __shared__ float row[VOC];            // 40 KB
    __shared__ float rm[4], rs_[4];
    const long long obase = (long long)blockIdx.x * VOC;
    const u16* lg = (const u16*)out + 2 * obase + VOC;  // bf16 logits row
    const int t = threadIdx.x;
    float m = -3.0e38f, s = 0.f;
    for (int i = t * 8; i < VOC; i += 2048) {
        const u16x8 h8 = *(const u16x8*)&lg[i];
        #pragma unroll
        for (int j = 0; j < 8; ++j) {
            const float xv = bf2f(h8[j]);
            row[i + j] = xv;
            const float d = xv - m;
            if (d > 0.f) { s = s * __expf(-d) + 1.f; m = xv; }
            else         { s += __expf(d); }
        }
    }
    #pragma unroll
    for (int o = 32; o; o >>= 1) {
        const float om = __shfl_down(m, o, 64), os = __shfl_down(s, o, 64);
        const float M = fmaxf(m, om);
        s = s * __expf(m - M) + os * __expf(om - M);
        m = M;
    }
    if ((t & 63) == 0) { rm[t >> 6] = m; rs_[t >> 6] = s; }
    __syncthreads();
    const float M = fmaxf(fmaxf(rm[0], rm[1]), fmaxf(rm[2], rm[3]));
    const float S = rs_[0]*__expf(rm[0]-M) + rs_[1]*__expf(rm[1]-M)
                  + rs_[2]*__expf(rm[2]-M) + rs_[3]*__expf(rm[3]-M);
    const float inv = 1.f / S;
    for (int i = t * 4; i < VOC; i += 1024) {
        float4 v = *(const float4*)&row[i];
        v.x = __expf(v.x - M) * inv;
        v.y = __expf(v.y - M) * inv;
        v.z = __expf(v.z - M) * inv;
        v.w = __expf(v.w - M) * inv;
        *(float4*)&out[obase + i] = v;
    }
}

// ---- host-side orchestration -------------------------------------------
extern "C" void kernel_launch(void* const* d_in, const int* in_sizes, int n_in,
                              void* d_out, int out_size, void* d_ws, size_t ws_size,
                              hipStream_t stream)
{
    const int*   x    = (const int*)  d_in[0];
    const int*   lens = (const int*)  d_in[1];
    const float* emb  = (const float*)d_in[2];
    const float* Wq   = (const float*)d_in[3];
    const float* bq   = (const float*)d_in[4];
    const float* Wk   = (const float*)d_in[5];
    const float* bk   = (const float*)d_in[6];
    const float* Wv   = (const float*)d_in[7];
    const float* bv   = (const float*)d_in[8];
    const float* W1   = (const float*)d_in[9];
    const float* b1   = (const float*)d_in[10];
    const float* W2   = (const float*)d_in[11];
    const float* b2   = (const float*)d_in[12];
    const float* g1   = (const float*)d_in[13];
    const float* be1  = (const float*)d_in[14];
    const float* g2   = (const float*)d_in[15];
    const float* be2  = (const float*)d_in[16];
    const float* fcw  = (const float*)d_in[17];
    const float* fcb  = (const float*)d_in[18];

    float* out = (float*)d_out;
    float* Zb     = out;
    float* O1f    = Zb + NH;
    float* M2f    = O1f + NH;
    float* BQKV   = M2f + NH;                       // [L][2304]
    u16* ub     = (u16*)(BQKV + (long long)LAYERS * 2304);
    u16* Zbh    = ub;  ub += NH;
    u16* QKVh   = ub;  ub += (long long)NROWS * 1536; // Q|K, ldc 1536
    u16* SCOREH = ub;  ub += SS8;                   // bf16 scores
    u16* ATTB   = ub;  ub += SS8;
    u16* Vt     = ub;  ub += NH;                    // [B][H][S]
    u16* O1h    = ub;  ub += NH;
    u16* M1h    = ub;  ub += NH;
    u16* WT     = ub;  ub += 41LL * WSZ;

    u16* ZFh = (u16*)d_ws;
    u16* EH  = ZFh + NH;
    const bool ehpath = ws_size >= (size_t)((NH + (long long)VOC * HID) * 2);
    u16* LOGH = (u16*)out + VOC;                    // bf16 logits, ldc 2*VOC

    const float scale = 1.0f / sqrtf((float)HID);
    const dim3 blk(256), blk128(128);

    embed_kernel<<<NROWS, blk, 0, stream>>>(x, emb, Zb, Zbh);
    transp_all<<<dim3(24, 24, 41), blk, 0, stream>>>(Wq, Wk, Wv, W1, W2, fcw, WT);
    pack_bias_all<<<dim3(3, LAYERS), dim3(768), 0, stream>>>(bq, bk, bv, BQKV);
    if (ehpath) convert_emb<<<7500, blk, 0, stream>>>(emb, EH);

    for (int l = 0; l < LAYERS; ++l) {
        const u16* wl = WT + (long long)l * 5 * WSZ;

        // qkv: Q,K -> QKVh[4096][1536]; V -> Vt transposed. XCD swizzle:
        // 576 = 8 x 72 blocks, A-panel sharers (same M-block) on one XCD.
        gemm_big<false, true, true><<<576, blk, 0, stream>>>(
            Zbh, wl, QKVh, 1536, 2304, HID,
            BQKV + (long long)l * 2304, Vt, 18);

        // scores = scale * Q @ K^T -> bf16
        gemm_small<false, true><<<dim3(8, 8, BATCH), blk128, 0, stream>>>(
            QKVh, 1536, (long long)SEQ * 1536,
            QKVh + 768, 1536, (long long)SEQ * 1536,
            SCOREH, SEQ, (long long)SEQ * SEQ,
            512, HID, nullptr, scale);

        softmax_q_kernel<<<dim3(BATCH, SEQ/16), blk, 0, stream>>>(SCOREH, ATTB, lens);

        // attnout = att @ V
        gemm_small<false, false><<<dim3(12, 8, BATCH), blk128, 0, stream>>>(
            ATTB, SEQ, (long long)SEQ * SEQ,
            Vt, SEQ, (long long)HID * SEQ,
            O1f, HID, (long long)SEQ * HID,
            768, SEQ, nullptr, 1.0f);

        ln_add_kernel<<<NROWS/4, blk, 0, stream>>>(Zb, O1f, O1f, O1h,
                                                   g1 + l*HID, be1 + l*HID);
        gemm_small<true, true><<<dim3(12, 64), blk128, 0, stream>>>(
            O1h, HID, 0, wl + 3*WSZ, HID, 0, M1h, HID, 0,
            768, HID, b1 + l*HID, 1.0f);
        gemm_small<false, false><<<dim3(12, 64), blk128, 0, stream>>>(
            M1h, HID, 0, wl + 4*WSZ, HID, 0, M2f, HID, 0,
            768, HID, b2 + l*HID, 1.0f);
        ln_add_kernel<<<NROWS/4, blk, 0, stream>>>(M2f, O1f, Zb, Zbh,
                                                   g2 + l*HID, be2 + l*HID);
    }

    // fc: zf = z @ fc_w + fc_b -> bf16 in d_ws
    gemm_small<false, true><<<dim3(12, 64), blk128, 0, stream>>>(
        Zbh, HID, 0, WT + 40LL*WSZ, HID, 0, ZFh, HID, 0,
        768, HID, fcb, 1.0f);

    // logits = zf @ emb^T -> bf16, row-local upper half of d_out.
    // XCD swizzle: 2560 = 8 x 320 blocks (y padded 79->80, OOB cols skip);
    // the 32 m-blocks sharing each emb B-panel land on ONE XCD's L2.
    if (ehpath) {
        gemm_big<true, false, true><<<2560, blk, 0, stream>>>(
            ZFh, EH, LOGH, 2*VOC, VOC, HID, nullptr, nullptr, 32);
    } else {
        gemm_conv<<<dim3(32, 79), blk, 0, stream>>>(ZFh, emb, LOGH);
    }

    softmax_v_kernel<<<NROWS, blk, 0, stream>>>(out);
}

// Round 14
// 1066.279 us; speedup vs baseline: 1.1724x; 1.0059x over previous
//
#include <hip/hip_runtime.h>
#include <math.h>

typedef unsigned int   u32;
typedef unsigned short u16;
typedef __attribute__((ext_vector_type(8))) short bf16x8;
typedef __attribute__((ext_vector_type(4))) float f32x4;
typedef __attribute__((ext_vector_type(4))) unsigned short u16x4;
typedef __attribute__((ext_vector_type(8))) unsigned short u16x8;

#define HID   768
#define SEQ   512
#define BATCH 8
#define LAYERS 8
#define VOC   10000
#define NROWS (BATCH*SEQ)             // 4096
#define NH    ((long long)NROWS*HID)  // 3,145,728
#define SS8   ((long long)BATCH*SEQ*SEQ)
#define EPSLN 1e-5f
#define WSZ   ((long long)HID*HID)    // 589824

__device__ __forceinline__ u16 f2bf(float f) {
    u32 u = __builtin_bit_cast(u32, f);
    return (u16)((u + 0x7fffu + ((u >> 16) & 1u)) >> 16);
}
__device__ __forceinline__ float bf2f(u16 h) {
    return __builtin_bit_cast(float, (u32)h << 16);
}

__device__ __forceinline__ void async16(u16* lds, const u16* g) {
    __builtin_amdgcn_global_load_lds(
        (const __attribute__((address_space(1))) u32*)g,
        (__attribute__((address_space(3))) u32*)lds, 16, 0, 0);
}

// ---- embedding + positional encoding (fp32 + bf16 shadow) ---------------
__global__ __launch_bounds__(256) void embed_kernel(
    const int* __restrict__ x, const float* __restrict__ emb,
    float* __restrict__ Z, u16* __restrict__ Zh)
{
    const int row = blockIdx.x;
    const int s   = row & (SEQ - 1);
    const int tok = x[row];
    const long long base  = (long long)row * HID;
    const long long ebase = (long long)tok * HID;
    const float coef = -0.0239852613853544f;   // -2*ln(10000)/768
    #pragma unroll
    for (int j = 0; j < 3; ++j) {
        const int h = threadIdx.x + 256 * j;
        const int i = h >> 1;
        const float ang = (float)s * expf((float)i * coef);
        const float pe  = (h & 1) ? cosf(ang) : sinf(ang);
        const float v = emb[ebase + h] + pe;
        Z[base + h]  = v;
        Zh[base + h] = f2bf(v);
    }
}

// ---- emb fp32 -> bf16, vectorized --------------------------------------
__global__ __launch_bounds__(256) void convert_emb(
    const float* __restrict__ e, u16* __restrict__ eh)
{
    const long long i = ((long long)blockIdx.x * 256 + threadIdx.x) * 4;
    const float4 v = *(const float4*)&e[i];
    u16x4 p;
    p[0] = f2bf(v.x); p[1] = f2bf(v.y); p[2] = f2bf(v.z); p[3] = f2bf(v.w);
    *(u16x4*)&eh[i] = p;
}

// ---- all-weights transpose+convert: fp32 [K,N] -> bf16 [N,K] ------------
__global__ __launch_bounds__(256) void transp_all(
    const float* __restrict__ Wq, const float* __restrict__ Wk,
    const float* __restrict__ Wv, const float* __restrict__ W1,
    const float* __restrict__ W2, const float* __restrict__ fcw,
    u16* __restrict__ WT)
{
    __shared__ u16 tile[32][34];
    const int z = blockIdx.z;
    const float* src;
    long long doff;
    if (z < 40) {
        const int lyr = z / 5, idx = z % 5;
        const float* bases[5] = {Wq, Wk, Wv, W1, W2};
        src  = bases[idx] + (long long)lyr * WSZ;
        doff = ((long long)lyr * 5 + idx) * WSZ;
    } else {
        src = fcw; doff = 40LL * WSZ;
    }
    u16* D = WT + doff;
    const int n0 = blockIdx.x * 32, k0 = blockIdx.y * 32;
    const int c = threadIdx.x & 31, r0 = threadIdx.x >> 5;
    #pragma unroll
    for (int p = 0; p < 4; ++p)
        tile[r0 + 8*p][c] = f2bf(src[(long long)(k0 + r0 + 8*p) * HID + n0 + c]);
    __syncthreads();
    #pragma unroll
    for (int p = 0; p < 4; ++p)
        D[(long long)(n0 + r0 + 8*p) * HID + k0 + c] = tile[c][r0 + 8*p];
}

// ---- pack qkv biases: [L][3*768] ---------------------------------------
__global__ void pack_bias_all(const float* __restrict__ bq,
                              const float* __restrict__ bk,
                              const float* __restrict__ bv,
                              float* __restrict__ dst)
{
    const int part = blockIdx.x, l = blockIdx.y, h = threadIdx.x;
    const float* src = part == 0 ? bq : (part == 1 ? bk : bv);
    dst[((long long)l*3 + part) * HID + h] = src[(long long)l*HID + h];
}

// ---- big MFMA GEMM: BM=BN=128, BK=32, 4 waves, row-major + XOR swizzle --
// (r10-verified: conflict-free, coalesced, best-so-far config)
template<bool XISM, bool VSPLIT>
__global__ __launch_bounds__(256) void gemm_big(
    const u16* __restrict__ A, const u16* __restrict__ B,
    u16* __restrict__ Cp, int ldc, int N, int K,
    const float* __restrict__ bias, u16* __restrict__ vt)
{
    __shared__ u16 As[2][128 * 32];   // 2 x 8 KB
    __shared__ u16 Bs[2][128 * 32];
    const int m0 = (XISM ? blockIdx.x : blockIdx.y) * 128;
    const int n0 = (XISM ? blockIdx.y : blockIdx.x) * 128;
    const int t = threadIdx.x, w = t >> 6, l = t & 63;
    const int lrow = l >> 2;                        // row within 16-row seg
    const int wm = (w >> 1) * 64, wn = (w & 1) * 64;

    f32x4 acc[4][4];
    #pragma unroll
    for (int mi = 0; mi < 4; ++mi)
        #pragma unroll
        for (int ni = 0; ni < 4; ++ni) acc[mi][ni] = (f32x4){0.f,0.f,0.f,0.f};

    auto stage = [&](int buf, int kt) {
        #pragma unroll
        for (int r = 0; r < 2; ++r) {
            const int seg = w * 2 + r;
            const int row = seg * 16 + lrow;
            const int gslot = (l & 3) ^ ((row >> 1) & 3);
            async16(&As[buf][seg * 512],
                    A + (long long)(m0 + row) * K + kt + gslot * 8);
        }
        #pragma unroll
        for (int r = 0; r < 2; ++r) {
            const int seg = w * 2 + r;
            const int row = seg * 16 + lrow;
            const int gslot = (l & 3) ^ ((row >> 1) & 3);
            int gr = n0 + row; gr = gr < N ? gr : N - 1;
            async16(&Bs[buf][seg * 512],
                    B + (long long)gr * K + kt + gslot * 8);
        }
    };
    const int fr = l & 15, fk = l >> 4;             // fragment row, k-slot
    auto compute = [&](int cur) {
        bf16x8 af[4], bfr[4];
        #pragma unroll
        for (int mi = 0; mi < 4; ++mi) {
            const int row = wm + mi*16 + fr;
            af[mi] = *(const bf16x8*)
                &As[cur][row * 32 + ((fk ^ ((row >> 1) & 3)) << 3)];
        }
        #pragma unroll
        for (int ni = 0; ni < 4; ++ni) {
            const int row = wn + ni*16 + fr;
            bfr[ni] = *(const bf16x8*)
                &Bs[cur][row * 32 + ((fk ^ ((row >> 1) & 3)) << 3)];
        }
        #pragma unroll
        for (int mi = 0; mi < 4; ++mi)
            #pragma unroll
            for (int ni = 0; ni < 4; ++ni)
                acc[mi][ni] = __builtin_amdgcn_mfma_f32_16x16x32_bf16(
                    af[mi], bfr[ni], acc[mi][ni], 0, 0, 0);
    };

    const int NS = K >> 5;                          // 24 tiles at K=768
    stage(0, 0);
    for (int tt = 0; tt < NS; ++tt) {
        if (tt + 1 < NS) {
            stage((tt + 1) & 1, (tt + 1) << 5);
            asm volatile("s_waitcnt vmcnt(4)\n\ts_barrier" ::: "memory");
        } else {
            asm volatile("s_waitcnt vmcnt(0)\n\ts_barrier" ::: "memory");
        }
        compute(tt & 1);
        asm volatile("s_barrier" ::: "memory");
    }

    const int fq = l >> 4;
    #pragma unroll
    for (int ni = 0; ni < 4; ++ni) {
        const int col = n0 + wn + ni*16 + fr;
        if (col >= N) continue;
        const float bv = bias ? bias[col] : 0.f;
        #pragma unroll
        for (int mi = 0; mi < 4; ++mi) {
            const int row0 = m0 + wm + mi*16 + fq*4;
            if constexpr (VSPLIT) {
                if (col < 1536) {
                    #pragma unroll
                    for (int v = 0; v < 4; ++v)
                        Cp[(long long)(row0 + v) * ldc + col] =
                            f2bf(acc[mi][ni][v] + bv);
                } else {
                    const int b9 = row0 >> 9, s9 = row0 & 511;
                    u16x4 pk;
                    #pragma unroll
                    for (int v = 0; v < 4; ++v)
                        pk[v] = f2bf(acc[mi][ni][v] + bv);
                    *(u16x4*)&vt[((long long)b9 * HID + (col - 1536)) * SEQ + s9] = pk;
                }
            } else {
                #pragma unroll
                for (int v = 0; v < 4; ++v)
                    Cp[(long long)(row0 + v) * ldc + col] =
                        f2bf(acc[mi][ni][v] + bv);
            }
        }
    }
}

// ---- small MFMA GEMM: BM=BN=64, BK=64, 2 waves, XOR-swizzled LDS --------
// (r5/r6/r10-verified)
template<bool RELU, bool OUT_BF16>
__global__ __launch_bounds__(128) void gemm_small(
    const u16* __restrict__ A, int lda, long long sA,
    const u16* __restrict__ B, int ldb, long long sB,
    void* __restrict__ Cp, int ldc, long long sC,
    int N, int K, const float* __restrict__ bias, float alpha)
{
    __shared__ u16 As[2][64 * 64];
    __shared__ u16 Bs[2][64 * 64];
    const int bz = blockIdx.z;
    const int n0 = blockIdx.x * 64;
    const int m0 = blockIdx.y * 64;
    const int t = threadIdx.x, w = t >> 6, l = t & 63;
    const int srow = l >> 3;                  // row within 8-row seg
    const int skof = ((l & 7) ^ srow) * 8;    // pre-swizzled global k-slot
    const int wm = w * 32;
    A += sA * bz; B += sB * bz;

    f32x4 acc[2][4];
    #pragma unroll
    for (int mi = 0; mi < 2; ++mi)
        #pragma unroll
        for (int ni = 0; ni < 4; ++ni) acc[mi][ni] = (f32x4){0.f,0.f,0.f,0.f};

    auto stage = [&](int buf, int k0) {
        #pragma unroll
        for (int r = 0; r < 4; ++r) {
            const int seg = w * 4 + r;
            const int row = seg * 8 + srow;
            async16(&As[buf][seg * 512],
                    A + (long long)(m0 + row) * lda + (k0 + skof));
        }
        #pragma unroll
        for (int r = 0; r < 4; ++r) {
            const int seg = w * 4 + r;
            const int row = seg * 8 + srow;
            async16(&Bs[buf][seg * 512],
                    B + (long long)(n0 + row) * ldb + (k0 + skof));
        }
    };
    const int fr = l & 15, fkb = l >> 4;      // logical slot base 0..3
    auto compute = [&](int cur) {
        #pragma unroll
        for (int ks = 0; ks < 2; ++ks) {
            const int ps = ((ks * 4 + fkb) ^ (fr & 7)) * 8;
            bf16x8 af[2], bfv[4];
            #pragma unroll
            for (int mi = 0; mi < 2; ++mi)
                af[mi] = *(const bf16x8*)&As[cur][(wm + mi*16 + fr) * 64 + ps];
            #pragma unroll
            for (int ni = 0; ni < 4; ++ni)
                bfv[ni] = *(const bf16x8*)&Bs[cur][(ni*16 + fr) * 64 + ps];
            #pragma unroll
            for (int mi = 0; mi < 2; ++mi)
                #pragma unroll
                for (int ni = 0; ni < 4; ++ni)
                    acc[mi][ni] = __builtin_amdgcn_mfma_f32_16x16x32_bf16(
                        af[mi], bfv[ni], acc[mi][ni], 0, 0, 0);
        }
    };

    const int NS = K >> 6;                    // 12 (K=768) or 8 (K=512)
    stage(0, 0);
    for (int tt = 0; tt < NS; ++tt) {
        if (tt + 1 < NS) {
            stage((tt + 1) & 1, (tt + 1) << 6);
            asm volatile("s_waitcnt vmcnt(8)\n\ts_barrier" ::: "memory");
        } else {
            asm volatile("s_waitcnt vmcnt(0)\n\ts_barrier" ::: "memory");
        }
        compute(tt & 1);
        asm volatile("s_barrier" ::: "memory");
    }

    float* Cf = (float*)Cp + sC * bz;
    u16*   Ch = (u16*)Cp + sC * bz;
    const int fq = l >> 4;
    #pragma unroll
    for (int ni = 0; ni < 4; ++ni) {
        const int col = n0 + ni*16 + fr;
        const float bv = bias ? bias[col] : 0.f;
        #pragma unroll
        for (int mi = 0; mi < 2; ++mi) {
            const int row0 = m0 + wm + mi*16 + fq*4;
            #pragma unroll
            for (int v = 0; v < 4; ++v) {
                float val = alpha * acc[mi][ni][v] + bv;
                if (RELU) val = fmaxf(val, 0.f);
                if (OUT_BF16) Ch[(long long)(row0 + v) * ldc + col] = f2bf(val);
                else          Cf[(long long)(row0 + v) * ldc + col] = val;
            }
        }
    }
}

// ---- fallback logits GEMM (fp32 B converted in-flight) -> bf16 out ------
__global__ __launch_bounds__(256) void gemm_conv(
    const u16* __restrict__ A, const float* __restrict__ Bf,
    u16* __restrict__ C)  // C = (u16*)out + VOC, ldc 2*VOC
{
    __shared__ u16 As[128 * 32];
    __shared__ u16 Bs[128 * 32];
    const int m0 = blockIdx.x * 128;
    const int n0 = blockIdx.y * 128;
    const int t = threadIdx.x, w = t >> 6, l = t & 63;
    const int lrow = l >> 2, lk8 = (l & 3) * 8;
    const int wm = (w >> 1) * 64, wn = (w & 1) * 64;
    f32x4 acc[4][4];
    #pragma unroll
    for (int mi = 0; mi < 4; ++mi)
        #pragma unroll
        for (int ni = 0; ni < 4; ++ni) acc[mi][ni] = (f32x4){0.f,0.f,0.f,0.f};

    for (int k0 = 0; k0 < HID; k0 += 32) {
        #pragma unroll
        for (int r = 0; r < 2; ++r) {
            const int seg = w * 2 + r;
            async16(&As[seg * 512],
                    A + (long long)(m0 + seg*16 + lrow) * HID + (k0 + lk8));
        }
        #pragma unroll
        for (int r = 0; r < 2; ++r) {
            const int flat = r * 2048 + t * 8;
            int row = n0 + (flat >> 5);
            row = row < VOC ? row : VOC - 1;
            const float* g = Bf + (long long)row * HID + (k0 + (flat & 31));
            const float4 v0 = *(const float4*)g;
            const float4 v1 = *(const float4*)(g + 4);
            bf16x8 hv;
            hv[0]=(short)f2bf(v0.x); hv[1]=(short)f2bf(v0.y);
            hv[2]=(short)f2bf(v0.z); hv[3]=(short)f2bf(v0.w);
            hv[4]=(short)f2bf(v1.x); hv[5]=(short)f2bf(v1.y);
            hv[6]=(short)f2bf(v1.z); hv[7]=(short)f2bf(v1.w);
            *(bf16x8*)&Bs[flat] = hv;
        }
        __syncthreads();
        const int fr = l & 15, fk = (l >> 4) * 8;
        bf16x8 af[4], bfr[4];
        #pragma unroll
        for (int mi = 0; mi < 4; ++mi)
            af[mi] = *(const bf16x8*)&As[(wm + mi*16 + fr) * 32 + fk];
        #pragma unroll
        for (int ni = 0; ni < 4; ++ni)
            bfr[ni] = *(const bf16x8*)&Bs[(wn + ni*16 + fr) * 32 + fk];
        #pragma unroll
        for (int mi = 0; mi < 4; ++mi)
            #pragma unroll
            for (int ni = 0; ni < 4; ++ni)
                acc[mi][ni] = __builtin_amdgcn_mfma_f32_16x16x32_bf16(
                    af[mi], bfr[ni], acc[mi][ni], 0, 0, 0);
        __syncthreads();
    }
    const int fr = l & 15, fq = l >> 4;
    #pragma unroll
    for (int ni = 0; ni < 4; ++ni) {
        const int col = n0 + wn + ni*16 + fr;
        if (col >= VOC) continue;
        #pragma unroll
        for (int mi = 0; mi < 4; ++mi) {
            const int row0 = m0 + wm + mi*16 + fq*4;
            #pragma unroll
            for (int v = 0; v < 4; ++v)
                C[(long long)(row0 + v) * (2*VOC) + col] = f2bf(acc[mi][ni][v]);
        }
    }
}

// ---- masked softmax over QUERY axis (dim=1): bf16 in, bf16 out ----------
__global__ __launch_bounds__(256) void softmax_q_kernel(
    const u16* __restrict__ sc, u16* __restrict__ att,
    const int* __restrict__ lengths)
{
    const int b  = blockIdx.x;
    const int k0 = blockIdx.y * 16;
    const int tx = threadIdx.x & 15;
    const int ty = threadIdx.x >> 4;
    const int c  = k0 + tx;
    const int len = lengths[b];
    const u16* base  = sc  + (long long)b * SEQ * SEQ;
    u16*       obase = att + (long long)b * SEQ * SEQ;
    const bool cvalid = (c < len);

    float vals[32];
    float m = -3.0e38f, ssum = 0.f;
    #pragma unroll
    for (int i = 0; i < 32; ++i) {
        const int q = ty + 16 * i;
        float xv = -3.0e38f;
        if (cvalid && c <= q && q < len)
            xv = bf2f(base[(long long)q * SEQ + c]);
        vals[i] = xv;
        if (xv > m) { ssum = ssum * __expf(m - xv) + 1.f; m = xv; }
        else if (xv > -3.0e38f) { ssum += __expf(xv - m); }
    }
    __shared__ float ms[16][17], ss[16][17];
    ms[ty][tx] = m; ss[ty][tx] = ssum;
    __syncthreads();
    if (ty == 0) {
        float M = ms[0][tx];
        #pragma unroll
        for (int r = 1; r < 16; ++r) M = fmaxf(M, ms[r][tx]);
        float Sx = 0.f;
        #pragma unroll
        for (int r = 0; r < 16; ++r) Sx += ss[r][tx] * __expf(ms[r][tx] - M);
        ms[0][tx] = M; ss[0][tx] = Sx;
    }
    __syncthreads();
    const float M   = ms[0][tx];
    const float den = ss[0][tx];
    const float inv = (den > 0.f) ? 1.f / den : 0.f;
    #pragma unroll
    for (int i = 0; i < 32; ++i) {
        const int q = ty + 16 * i;
        obase[(long long)q * SEQ + c] = f2bf(__expf(vals[i] - M) * inv);
    }
}

// ---- fused residual-add + LayerNorm: wave-per-row, float4, no barriers --
__global__ __launch_bounds__(256) void ln_add_kernel(
    const float* __restrict__ Xa, const float* __restrict__ Xb,
    float* __restrict__ O, u16* __restrict__ Oh,
    const float* __restrict__ g, const float* __restrict__ be)
{
    const int row = blockIdx.x * 4 + (threadIdx.x >> 6);
    const int l = threadIdx.x & 63;
    const long long base = (long long)row * HID;
    float x[12];
    #pragma unroll
    for (int c = 0; c < 3; ++c) {
        const int off = c * 256 + l * 4;
        const float4 a = *(const float4*)&Xa[base + off];
        const float4 b = *(const float4*)&Xb[base + off];
        x[c*4+0] = a.x + b.x; x[c*4+1] = a.y + b.y;
        x[c*4+2] = a.z + b.z; x[c*4+3] = a.w + b.w;
    }
    float s = 0.f;
    #pragma unroll
    for (int i = 0; i < 12; ++i) s += x[i];
    #pragma unroll
    for (int o = 32; o; o >>= 1) s += __shfl_xor(s, o, 64);
    const float mean = s * (1.f / HID);
    float v = 0.f;
    #pragma unroll
    for (int i = 0; i < 12; ++i) { const float d = x[i] - mean; v += d * d; }
    #pragma unroll
    for (int o = 32; o; o >>= 1) v += __shfl_xor(v, o, 64);
    const float rs = rsqrtf(v * (1.f / HID) + EPSLN);
    #pragma unroll
    for (int c = 0; c < 3; ++c) {
        const int off = c * 256 + l * 4;
        const float4 gg = *(const float4*)&g[off];
        const float4 bb = *(const float4*)&be[off];
        float4 y;
        y.x = (x[c*4+0] - mean) * rs * gg.x + bb.x;
        y.y = (x[c*4+1] - mean) * rs * gg.y + bb.y;
        y.z = (x[c*4+2] - mean) * rs * gg.z + bb.z;
        y.w = (x[c*4+3] - mean) * rs * gg.w + bb.w;
        *(float4*)&O[base + off] = y;
        u16x4 p;
        p[0] = f2bf(y.x); p[1] = f2bf(y.y); p[2] = f2bf(y.z); p[3] = f2bf(y.w);
        *(u16x4*)&Oh[base + off] = p;
    }
}

// ---- vocab softmax: bf16 logits in (row-local upper half), fp32 out -----
__global__ __launch_bounds__(256) void softmax_v_kernel(float* __restrict__ out)
{
    __shared__ float row[VOC];            // 40 KB
    __shared__ float rm[4], rs_[4];
    const long long obase = (long long)blockIdx.x * VOC;
    const u16* lg = (const u16*)out + 2 * obase + VOC;  // bf16 logits row
    const int t = threadIdx.x;
    float m = -3.0e38f, s = 0.f;
    for (int i = t * 8; i < VOC; i += 2048) {
        const u16x8 h8 = *(const u16x8*)&lg[i];
        #pragma unroll
        for (int j = 0; j < 8; ++j) {
            const float xv = bf2f(h8[j]);
            row[i + j] = xv;
            const float d = xv - m;
            if (d > 0.f) { s = s * __expf(-d) + 1.f; m = xv; }
            else         { s += __expf(d); }
        }
    }
    #pragma unroll
    for (int o = 32; o; o >>= 1) {
        const float om = __shfl_down(m, o, 64), os = __shfl_down(s, o, 64);
        const float M = fmaxf(m, om);
        s = s * __expf(m - M) + os * __expf(om - M);
        m = M;
    }
    if ((t & 63) == 0) { rm[t >> 6] = m; rs_[t >> 6] = s; }
    __syncthreads();
    const float M = fmaxf(fmaxf(rm[0], rm[1]), fmaxf(rm[2], rm[3]));
    const float S = rs_[0]*__expf(rm[0]-M) + rs_[1]*__expf(rm[1]-M)
                  + rs_[2]*__expf(rm[2]-M) + rs_[3]*__expf(rm[3]-M);
    const float inv = 1.f / S;
    for (int i = t * 4; i < VOC; i += 1024) {
        float4 v = *(const float4*)&row[i];
        v.x = __expf(v.x - M) * inv;
        v.y = __expf(v.y - M) * inv;
        v.z = __expf(v.z - M) * inv;
        v.w = __expf(v.w - M) * inv;
        *(float4*)&out[obase + i] = v;
    }
}

// ---- host-side orchestration -------------------------------------------
extern "C" void kernel_launch(void* const* d_in, const int* in_sizes, int n_in,
                              void* d_out, int out_size, void* d_ws, size_t ws_size,
                              hipStream_t stream)
{
    const int*   x    = (const int*)  d_in[0];
    const int*   lens = (const int*)  d_in[1];
    const float* emb  = (const float*)d_in[2];
    const float* Wq   = (const float*)d_in[3];
    const float* bq   = (const float*)d_in[4];
    const float* Wk   = (const float*)d_in[5];
    const float* bk   = (const float*)d_in[6];
    const float* Wv   = (const float*)d_in[7];
    const float* bv   = (const float*)d_in[8];
    const float* W1   = (const float*)d_in[9];
    const float* b1   = (const float*)d_in[10];
    const float* W2   = (const float*)d_in[11];
    const float* b2   = (const float*)d_in[12];
    const float* g1   = (const float*)d_in[13];
    const float* be1  = (const float*)d_in[14];
    const float* g2   = (const float*)d_in[15];
    const float* be2  = (const float*)d_in[16];
    const float* fcw  = (const float*)d_in[17];
    const float* fcb  = (const float*)d_in[18];

    float* out = (float*)d_out;
    float* Zb     = out;
    float* O1f    = Zb + NH;
    float* M2f    = O1f + NH;
    float* BQKV   = M2f + NH;                       // [L][2304]
    u16* ub     = (u16*)(BQKV + (long long)LAYERS * 2304);
    u16* Zbh    = ub;  ub += NH;
    u16* QKVh   = ub;  ub += (long long)NROWS * 1536; // Q|K, ldc 1536
    u16* SCOREH = ub;  ub += SS8;                   // bf16 scores
    u16* ATTB   = ub;  ub += SS8;
    u16* Vt     = ub;  ub += NH;                    // [B][H][S]
    u16* O1h    = ub;  ub += NH;
    u16* M1h    = ub;  ub += NH;
    u16* WT     = ub;  ub += 41LL * WSZ;

    u16* ZFh = (u16*)d_ws;
    u16* EH  = ZFh + NH;
    const bool ehpath = ws_size >= (size_t)((NH + (long long)VOC * HID) * 2);
    u16* LOGH = (u16*)out + VOC;                    // bf16 logits, ldc 2*VOC

    const float scale = 1.0f / sqrtf((float)HID);
    const dim3 blk(256), blk128(128);

    embed_kernel<<<NROWS, blk, 0, stream>>>(x, emb, Zb, Zbh);
    transp_all<<<dim3(24, 24, 41), blk, 0, stream>>>(Wq, Wk, Wv, W1, W2, fcw, WT);
    pack_bias_all<<<dim3(3, LAYERS), dim3(768), 0, stream>>>(bq, bk, bv, BQKV);
    if (ehpath) convert_emb<<<7500, blk, 0, stream>>>(emb, EH);

    for (int l = 0; l < LAYERS; ++l) {
        const u16* wl = WT + (long long)l * 5 * WSZ;

        // qkv: Q,K -> QKVh[4096][1536]; V -> Vt transposed.
        gemm_big<false, true><<<dim3(18, 32), blk, 0, stream>>>(
            Zbh, wl, QKVh, 1536, 2304, HID,
            BQKV + (long long)l * 2304, Vt);

        // scores = scale * Q @ K^T -> bf16
        gemm_small<false, true><<<dim3(8, 8, BATCH), blk128, 0, stream>>>(
            QKVh, 1536, (long long)SEQ * 1536,
            QKVh + 768, 1536, (long long)SEQ * 1536,
            SCOREH, SEQ, (long long)SEQ * SEQ,
            512, HID, nullptr, scale);

        softmax_q_kernel<<<dim3(BATCH, SEQ/16), blk, 0, stream>>>(SCOREH, ATTB, lens);

        // attnout = att @ V
        gemm_small<false, false><<<dim3(12, 8, BATCH), blk128, 0, stream>>>(
            ATTB, SEQ, (long long)SEQ * SEQ,
            Vt, SEQ, (long long)HID * SEQ,
            O1f, HID, (long long)SEQ * HID,
            768, SEQ, nullptr, 1.0f);

        ln_add_kernel<<<NROWS/4, blk, 0, stream>>>(Zb, O1f, O1f, O1h,
                                                   g1 + l*HID, be1 + l*HID);
        gemm_small<true, true><<<dim3(12, 64), blk128, 0, stream>>>(
            O1h, HID, 0, wl + 3*WSZ, HID, 0, M1h, HID, 0,
            768, HID, b1 + l*HID, 1.0f);
        gemm_small<false, false><<<dim3(12, 64), blk128, 0, stream>>>(
            M1h, HID, 0, wl + 4*WSZ, HID, 0, M2f, HID, 0,
            768, HID, b2 + l*HID, 1.0f);
        ln_add_kernel<<<NROWS/4, blk, 0, stream>>>(M2f, O1f, Zb, Zbh,
                                                   g2 + l*HID, be2 + l*HID);
    }

    // fc: zf = z @ fc_w + fc_b -> bf16 in d_ws
    gemm_small<false, true><<<dim3(12, 64), blk128, 0, stream>>>(
        Zbh, HID, 0, WT + 40LL*WSZ, HID, 0, ZFh, HID, 0,
        768, HID, fcb, 1.0f);

    // logits = zf @ emb^T -> bf16, row-local upper half of d_out.
    // XISM 2-D grid: consecutive blocks share the emb B-panel (L2 reuse).
    if (ehpath) {
        gemm_big<true, false><<<dim3(32, 79), blk, 0, stream>>>(
            ZFh, EH, LOGH, 2*VOC, VOC, HID, nullptr, nullptr);
    } else {
        gemm_conv<<<dim3(32, 79), blk, 0, stream>>>(ZFh, emb, LOGH);
    }

    softmax_v_kernel<<<NROWS, blk, 0, stream>>>(out);
}

// Round 15
// 1042.515 us; speedup vs baseline: 1.1992x; 1.0228x over previous
//
#include <hip/hip_runtime.h>
#include <math.h>

typedef unsigned int   u32;
typedef unsigned short u16;
typedef __attribute__((ext_vector_type(8))) short bf16x8;
typedef __attribute__((ext_vector_type(4))) float f32x4;
typedef __attribute__((ext_vector_type(4))) unsigned short u16x4;
typedef __attribute__((ext_vector_type(8))) unsigned short u16x8;

#define HID   768
#define SEQ   512
#define BATCH 8
#define LAYERS 8
#define VOC   10000
#define NROWS (BATCH*SEQ)             // 4096
#define NH    ((long long)NROWS*HID)  // 3,145,728
#define SS8   ((long long)BATCH*SEQ*SEQ)
#define EPSLN 1e-5f
#define WSZ   ((long long)HID*HID)    // 589824

__device__ __forceinline__ u16 f2bf(float f) {
    u32 u = __builtin_bit_cast(u32, f);
    return (u16)((u + 0x7fffu + ((u >> 16) & 1u)) >> 16);
}
__device__ __forceinline__ float bf2f(u16 h) {
    return __builtin_bit_cast(float, (u32)h << 16);
}

__device__ __forceinline__ void async16(u16* lds, const u16* g) {
    __builtin_amdgcn_global_load_lds(
        (const __attribute__((address_space(1))) u32*)g,
        (__attribute__((address_space(3))) u32*)lds, 16, 0, 0);
}

// ---- embedding + positional encoding (fp32 + bf16 shadow) ---------------
__global__ __launch_bounds__(256) void embed_kernel(
    const int* __restrict__ x, const float* __restrict__ emb,
    float* __restrict__ Z, u16* __restrict__ Zh)
{
    const int row = blockIdx.x;
    const int s   = row & (SEQ - 1);
    const int tok = x[row];
    const long long base  = (long long)row * HID;
    const long long ebase = (long long)tok * HID;
    const float coef = -0.0239852613853544f;   // -2*ln(10000)/768
    #pragma unroll
    for (int j = 0; j < 3; ++j) {
        const int h = threadIdx.x + 256 * j;
        const int i = h >> 1;
        const float ang = (float)s * expf((float)i * coef);
        const float pe  = (h & 1) ? cosf(ang) : sinf(ang);
        const float v = emb[ebase + h] + pe;
        Z[base + h]  = v;
        Zh[base + h] = f2bf(v);
    }
}

// ---- emb fp32 -> bf16, vectorized --------------------------------------
__global__ __launch_bounds__(256) void convert_emb(
    const float* __restrict__ e, u16* __restrict__ eh)
{
    const long long i = ((long long)blockIdx.x * 256 + threadIdx.x) * 4;
    const float4 v = *(const float4*)&e[i];
    u16x4 p;
    p[0] = f2bf(v.x); p[1] = f2bf(v.y); p[2] = f2bf(v.z); p[3] = f2bf(v.w);
    *(u16x4*)&eh[i] = p;
}

// ---- all-weights transpose+convert: fp32 [K,N] -> bf16 [N,K] ------------
__global__ __launch_bounds__(256) void transp_all(
    const float* __restrict__ Wq, const float* __restrict__ Wk,
    const float* __restrict__ Wv, const float* __restrict__ W1,
    const float* __restrict__ W2, const float* __restrict__ fcw,
    u16* __restrict__ WT)
{
    __shared__ u16 tile[32][34];
    const int z = blockIdx.z;
    const float* src;
    long long doff;
    if (z < 40) {
        const int lyr = z / 5, idx = z % 5;
        const float* bases[5] = {Wq, Wk, Wv, W1, W2};
        src  = bases[idx] + (long long)lyr * WSZ;
        doff = ((long long)lyr * 5 + idx) * WSZ;
    } else {
        src = fcw; doff = 40LL * WSZ;
    }
    u16* D = WT + doff;
    const int n0 = blockIdx.x * 32, k0 = blockIdx.y * 32;
    const int c = threadIdx.x & 31, r0 = threadIdx.x >> 5;
    #pragma unroll
    for (int p = 0; p < 4; ++p)
        tile[r0 + 8*p][c] = f2bf(src[(long long)(k0 + r0 + 8*p) * HID + n0 + c]);
    __syncthreads();
    #pragma unroll
    for (int p = 0; p < 4; ++p)
        D[(long long)(n0 + r0 + 8*p) * HID + k0 + c] = tile[c][r0 + 8*p];
}

// ---- pack qkv biases: [L][3*768] ---------------------------------------
__global__ void pack_bias_all(const float* __restrict__ bq,
                              const float* __restrict__ bk,
                              const float* __restrict__ bv,
                              float* __restrict__ dst)
{
    const int part = blockIdx.x, l = blockIdx.y, h = threadIdx.x;
    const float* src = part == 0 ? bq : (part == 1 ? bk : bv);
    dst[((long long)l*3 + part) * HID + h] = src[(long long)l*HID + h];
}

// ---- big MFMA GEMM: BM=BN=128, BK=32, 4 waves, row-major + XOR swizzle --
// (r10-verified: conflict-free, coalesced, best-so-far config)
template<bool XISM, bool VSPLIT>
__global__ __launch_bounds__(256) void gemm_big(
    const u16* __restrict__ A, const u16* __restrict__ B,
    u16* __restrict__ Cp, int ldc, int N, int K,
    const float* __restrict__ bias, u16* __restrict__ vt)
{
    __shared__ u16 As[2][128 * 32];   // 2 x 8 KB
    __shared__ u16 Bs[2][128 * 32];
    const int m0 = (XISM ? blockIdx.x : blockIdx.y) * 128;
    const int n0 = (XISM ? blockIdx.y : blockIdx.x) * 128;
    const int t = threadIdx.x, w = t >> 6, l = t & 63;
    const int lrow = l >> 2;                        // row within 16-row seg
    const int wm = (w >> 1) * 64, wn = (w & 1) * 64;

    f32x4 acc[4][4];
    #pragma unroll
    for (int mi = 0; mi < 4; ++mi)
        #pragma unroll
        for (int ni = 0; ni < 4; ++ni) acc[mi][ni] = (f32x4){0.f,0.f,0.f,0.f};

    auto stage = [&](int buf, int kt) {
        #pragma unroll
        for (int r = 0; r < 2; ++r) {
            const int seg = w * 2 + r;
            const int row = seg * 16 + lrow;
            const int gslot = (l & 3) ^ ((row >> 1) & 3);
            async16(&As[buf][seg * 512],
                    A + (long long)(m0 + row) * K + kt + gslot * 8);
        }
        #pragma unroll
        for (int r = 0; r < 2; ++r) {
            const int seg = w * 2 + r;
            const int row = seg * 16 + lrow;
            const int gslot = (l & 3) ^ ((row >> 1) & 3);
            int gr = n0 + row; gr = gr < N ? gr : N - 1;
            async16(&Bs[buf][seg * 512],
                    B + (long long)gr * K + kt + gslot * 8);
        }
    };
    const int fr = l & 15, fk = l >> 4;             // fragment row, k-slot
    auto compute = [&](int cur) {
        bf16x8 af[4], bfr[4];
        #pragma unroll
        for (int mi = 0; mi < 4; ++mi) {
            const int row = wm + mi*16 + fr;
            af[mi] = *(const bf16x8*)
                &As[cur][row * 32 + ((fk ^ ((row >> 1) & 3)) << 3)];
        }
        #pragma unroll
        for (int ni = 0; ni < 4; ++ni) {
            const int row = wn + ni*16 + fr;
            bfr[ni] = *(const bf16x8*)
                &Bs[cur][row * 32 + ((fk ^ ((row >> 1) & 3)) << 3)];
        }
        #pragma unroll
        for (int mi = 0; mi < 4; ++mi)
            #pragma unroll
            for (int ni = 0; ni < 4; ++ni)
                acc[mi][ni] = __builtin_amdgcn_mfma_f32_16x16x32_bf16(
                    af[mi], bfr[ni], acc[mi][ni], 0, 0, 0);
    };

    const int NS = K >> 5;                          // 24 tiles at K=768
    stage(0, 0);
    for (int tt = 0; tt < NS; ++tt) {
        if (tt + 1 < NS) {
            stage((tt + 1) & 1, (tt + 1) << 5);
            asm volatile("s_waitcnt vmcnt(4)\n\ts_barrier" ::: "memory");
        } else {
            asm volatile("s_waitcnt vmcnt(0)\n\ts_barrier" ::: "memory");
        }
        compute(tt & 1);
        asm volatile("s_barrier" ::: "memory");
    }

    const int fq = l >> 4;
    #pragma unroll
    for (int ni = 0; ni < 4; ++ni) {
        const int col = n0 + wn + ni*16 + fr;
        if (col >= N) continue;
        const float bv = bias ? bias[col] : 0.f;
        #pragma unroll
        for (int mi = 0; mi < 4; ++mi) {
            const int row0 = m0 + wm + mi*16 + fq*4;
            if constexpr (VSPLIT) {
                if (col < 1536) {
                    #pragma unroll
                    for (int v = 0; v < 4; ++v)
                        Cp[(long long)(row0 + v) * ldc + col] =
                            f2bf(acc[mi][ni][v] + bv);
                } else {
                    const int b9 = row0 >> 9, s9 = row0 & 511;
                    u16x4 pk;
                    #pragma unroll
                    for (int v = 0; v < 4; ++v)
                        pk[v] = f2bf(acc[mi][ni][v] + bv);
                    *(u16x4*)&vt[((long long)b9 * HID + (col - 1536)) * SEQ + s9] = pk;
                }
            } else {
                #pragma unroll
                for (int v = 0; v < 4; ++v)
                    Cp[(long long)(row0 + v) * ldc + col] =
                        f2bf(acc[mi][ni][v] + bv);
            }
        }
    }
}

// ---- small MFMA GEMM: BM=BN=64, BK=64, 2 waves, XOR-swizzled LDS --------
// (r5/r6/r10-verified)
template<bool RELU, bool OUT_BF16>
__global__ __launch_bounds__(128) void gemm_small(
    const u16* __restrict__ A, int lda, long long sA,
    const u16* __restrict__ B, int ldb, long long sB,
    void* __restrict__ Cp, int ldc, long long sC,
    int N, int K, const float* __restrict__ bias, float alpha)
{
    __shared__ u16 As[2][64 * 64];
    __shared__ u16 Bs[2][64 * 64];
    const int bz = blockIdx.z;
    const int n0 = blockIdx.x * 64;
    const int m0 = blockIdx.y * 64;
    const int t = threadIdx.x, w = t >> 6, l = t & 63;
    const int srow = l >> 3;                  // row within 8-row seg
    const int skof = ((l & 7) ^ srow) * 8;    // pre-swizzled global k-slot
    const int wm = w * 32;
    A += sA * bz; B += sB * bz;

    f32x4 acc[2][4];
    #pragma unroll
    for (int mi = 0; mi < 2; ++mi)
        #pragma unroll
        for (int ni = 0; ni < 4; ++ni) acc[mi][ni] = (f32x4){0.f,0.f,0.f,0.f};

    auto stage = [&](int buf, int k0) {
        #pragma unroll
        for (int r = 0; r < 4; ++r) {
            const int seg = w * 4 + r;
            const int row = seg * 8 + srow;
            async16(&As[buf][seg * 512],
                    A + (long long)(m0 + row) * lda + (k0 + skof));
        }
        #pragma unroll
        for (int r = 0; r < 4; ++r) {
            const int seg = w * 4 + r;
            const int row = seg * 8 + srow;
            async16(&Bs[buf][seg * 512],
                    B + (long long)(n0 + row) * ldb + (k0 + skof));
        }
    };
    const int fr = l & 15, fkb = l >> 4;      // logical slot base 0..3
    auto compute = [&](int cur) {
        #pragma unroll
        for (int ks = 0; ks < 2; ++ks) {
            const int ps = ((ks * 4 + fkb) ^ (fr & 7)) * 8;
            bf16x8 af[2], bfv[4];
            #pragma unroll
            for (int mi = 0; mi < 2; ++mi)
                af[mi] = *(const bf16x8*)&As[cur][(wm + mi*16 + fr) * 64 + ps];
            #pragma unroll
            for (int ni = 0; ni < 4; ++ni)
                bfv[ni] = *(const bf16x8*)&Bs[cur][(ni*16 + fr) * 64 + ps];
            #pragma unroll
            for (int mi = 0; mi < 2; ++mi)
                #pragma unroll
                for (int ni = 0; ni < 4; ++ni)
                    acc[mi][ni] = __builtin_amdgcn_mfma_f32_16x16x32_bf16(
                        af[mi], bfv[ni], acc[mi][ni], 0, 0, 0);
        }
    };

    const int NS = K >> 6;                    // 12 (K=768) or 8 (K=512)
    stage(0, 0);
    for (int tt = 0; tt < NS; ++tt) {
        if (tt + 1 < NS) {
            stage((tt + 1) & 1, (tt + 1) << 6);
            asm volatile("s_waitcnt vmcnt(8)\n\ts_barrier" ::: "memory");
        } else {
            asm volatile("s_waitcnt vmcnt(0)\n\ts_barrier" ::: "memory");
        }
        compute(tt & 1);
        asm volatile("s_barrier" ::: "memory");
    }

    float* Cf = (float*)Cp + sC * bz;
    u16*   Ch = (u16*)Cp + sC * bz;
    const int fq = l >> 4;
    #pragma unroll
    for (int ni = 0; ni < 4; ++ni) {
        const int col = n0 + ni*16 + fr;
        const float bv = bias ? bias[col] : 0.f;
        #pragma unroll
        for (int mi = 0; mi < 2; ++mi) {
            const int row0 = m0 + wm + mi*16 + fq*4;
            #pragma unroll
            for (int v = 0; v < 4; ++v) {
                float val = alpha * acc[mi][ni][v] + bv;
                if (RELU) val = fmaxf(val, 0.f);
                if (OUT_BF16) Ch[(long long)(row0 + v) * ldc + col] = f2bf(val);
                else          Cf[(long long)(row0 + v) * ldc + col] = val;
            }
        }
    }
}

// ---- fallback logits GEMM (fp32 B converted in-flight) -> bf16 out ------
__global__ __launch_bounds__(256) void gemm_conv(
    const u16* __restrict__ A, const float* __restrict__ Bf,
    u16* __restrict__ C)  // C = (u16*)out + VOC, ldc 2*VOC
{
    __shared__ u16 As[128 * 32];
    __shared__ u16 Bs[128 * 32];
    const int m0 = blockIdx.x * 128;
    const int n0 = blockIdx.y * 128;
    const int t = threadIdx.x, w = t >> 6, l = t & 63;
    const int lrow = l >> 2, lk8 = (l & 3) * 8;
    const int wm = (w >> 1) * 64, wn = (w & 1) * 64;
    f32x4 acc[4][4];
    #pragma unroll
    for (int mi = 0; mi < 4; ++mi)
        #pragma unroll
        for (int ni = 0; ni < 4; ++ni) acc[mi][ni] = (f32x4){0.f,0.f,0.f,0.f};

    for (int k0 = 0; k0 < HID; k0 += 32) {
        #pragma unroll
        for (int r = 0; r < 2; ++r) {
            const int seg = w * 2 + r;
            async16(&As[seg * 512],
                    A + (long long)(m0 + seg*16 + lrow) * HID + (k0 + lk8));
        }
        #pragma unroll
        for (int r = 0; r < 2; ++r) {
            const int flat = r * 2048 + t * 8;
            int row = n0 + (flat >> 5);
            row = row < VOC ? row : VOC - 1;
            const float* g = Bf + (long long)row * HID + (k0 + (flat & 31));
            const float4 v0 = *(const float4*)g;
            const float4 v1 = *(const float4*)(g + 4);
            bf16x8 hv;
            hv[0]=(short)f2bf(v0.x); hv[1]=(short)f2bf(v0.y);
            hv[2]=(short)f2bf(v0.z); hv[3]=(short)f2bf(v0.w);
            hv[4]=(short)f2bf(v1.x); hv[5]=(short)f2bf(v1.y);
            hv[6]=(short)f2bf(v1.z); hv[7]=(short)f2bf(v1.w);
            *(bf16x8*)&Bs[flat] = hv;
        }
        __syncthreads();
        const int fr = l & 15, fk = (l >> 4) * 8;
        bf16x8 af[4], bfr[4];
        #pragma unroll
        for (int mi = 0; mi < 4; ++mi)
            af[mi] = *(const bf16x8*)&As[(wm + mi*16 + fr) * 32 + fk];
        #pragma unroll
        for (int ni = 0; ni < 4; ++ni)
            bfr[ni] = *(const bf16x8*)&Bs[(wn + ni*16 + fr) * 32 + fk];
        #pragma unroll
        for (int mi = 0; mi < 4; ++mi)
            #pragma unroll
            for (int ni = 0; ni < 4; ++ni)
                acc[mi][ni] = __builtin_amdgcn_mfma_f32_16x16x32_bf16(
                    af[mi], bfr[ni], acc[mi][ni], 0, 0, 0);
        __syncthreads();
    }
    const int fr = l & 15, fq = l >> 4;
    #pragma unroll
    for (int ni = 0; ni < 4; ++ni) {
        const int col = n0 + wn + ni*16 + fr;
        if (col >= VOC) continue;
        #pragma unroll
        for (int mi = 0; mi < 4; ++mi) {
            const int row0 = m0 + wm + mi*16 + fq*4;
            #pragma unroll
            for (int v = 0; v < 4; ++v)
                C[(long long)(row0 + v) * (2*VOC) + col] = f2bf(acc[mi][ni][v]);
        }
    }
}

// ---- masked softmax over QUERY axis (dim=1): bf16 in, bf16 out ----------
__global__ __launch_bounds__(256) void softmax_q_kernel(
    const u16* __restrict__ sc, u16* __restrict__ att,
    const int* __restrict__ lengths)
{
    const int b  = blockIdx.x;
    const int k0 = blockIdx.y * 16;
    const int tx = threadIdx.x & 15;
    const int ty = threadIdx.x >> 4;
    const int c  = k0 + tx;
    const int len = lengths[b];
    const u16* base  = sc  + (long long)b * SEQ * SEQ;
    u16*       obase = att + (long long)b * SEQ * SEQ;
    const bool cvalid = (c < len);

    float vals[32];
    float m = -3.0e38f, ssum = 0.f;
    #pragma unroll
    for (int i = 0; i < 32; ++i) {
        const int q = ty + 16 * i;
        float xv = -3.0e38f;
        if (cvalid && c <= q && q < len)
            xv = bf2f(base[(long long)q * SEQ + c]);
        vals[i] = xv;
        if (xv > m) { ssum = ssum * __expf(m - xv) + 1.f; m = xv; }
        else if (xv > -3.0e38f) { ssum += __expf(xv - m); }
    }
    __shared__ float ms[16][17], ss[16][17];
    ms[ty][tx] = m; ss[ty][tx] = ssum;
    __syncthreads();
    if (ty == 0) {
        float M = ms[0][tx];
        #pragma unroll
        for (int r = 1; r < 16; ++r) M = fmaxf(M, ms[r][tx]);
        float Sx = 0.f;
        #pragma unroll
        for (int r = 0; r < 16; ++r) Sx += ss[r][tx] * __expf(ms[r][tx] - M);
        ms[0][tx] = M; ss[0][tx] = Sx;
    }
    __syncthreads();
    const float M   = ms[0][tx];
    const float den = ss[0][tx];
    const float inv = (den > 0.f) ? 1.f / den : 0.f;
    #pragma unroll
    for (int i = 0; i < 32; ++i) {
        const int q = ty + 16 * i;
        obase[(long long)q * SEQ + c] = f2bf(__expf(vals[i] - M) * inv);
    }
}

// ---- fused residual-add + LayerNorm: Xa fp32, Xb BF16; wave-per-row -----
__global__ __launch_bounds__(256) void ln_add_b_kernel(
    const float* __restrict__ Xa, const u16* __restrict__ Xb,
    float* __restrict__ O, u16* __restrict__ Oh,
    const float* __restrict__ g, const float* __restrict__ be)
{
    const int row = blockIdx.x * 4 + (threadIdx.x >> 6);
    const int l = threadIdx.x & 63;
    const long long base = (long long)row * HID;
    float x[12];
    #pragma unroll
    for (int c = 0; c < 3; ++c) {
        const int off = c * 256 + l * 4;
        const float4 a = *(const float4*)&Xa[base + off];
        const u16x4  b = *(const u16x4*)&Xb[base + off];
        x[c*4+0] = a.x + bf2f(b[0]); x[c*4+1] = a.y + bf2f(b[1]);
        x[c*4+2] = a.z + bf2f(b[2]); x[c*4+3] = a.w + bf2f(b[3]);
    }
    float s = 0.f;
    #pragma unroll
    for (int i = 0; i < 12; ++i) s += x[i];
    #pragma unroll
    for (int o = 32; o; o >>= 1) s += __shfl_xor(s, o, 64);
    const float mean = s * (1.f / HID);
    float v = 0.f;
    #pragma unroll
    for (int i = 0; i < 12; ++i) { const float d = x[i] - mean; v += d * d; }
    #pragma unroll
    for (int o = 32; o; o >>= 1) v += __shfl_xor(v, o, 64);
    const float rs = rsqrtf(v * (1.f / HID) + EPSLN);
    #pragma unroll
    for (int c = 0; c < 3; ++c) {
        const int off = c * 256 + l * 4;
        const float4 gg = *(const float4*)&g[off];
        const float4 bb = *(const float4*)&be[off];
        float4 y;
        y.x = (x[c*4+0] - mean) * rs * gg.x + bb.x;
        y.y = (x[c*4+1] - mean) * rs * gg.y + bb.y;
        y.z = (x[c*4+2] - mean) * rs * gg.z + bb.z;
        y.w = (x[c*4+3] - mean) * rs * gg.w + bb.w;
        *(float4*)&O[base + off] = y;
        u16x4 p;
        p[0] = f2bf(y.x); p[1] = f2bf(y.y); p[2] = f2bf(y.z); p[3] = f2bf(y.w);
        *(u16x4*)&Oh[base + off] = p;
    }
}

// ---- vocab softmax: bf16 logits in (row-local upper half), fp32 out -----
__global__ __launch_bounds__(256) void softmax_v_kernel(float* __restrict__ out)
{
    __shared__ float row[VOC];            // 40 KB
    __shared__ float rm[4], rs_[4];
    const long long obase = (long long)blockIdx.x * VOC;
    const u16* lg = (const u16*)out + 2 * obase + VOC;  // bf16 logits row
    const int t = threadIdx.x;
    float m = -3.0e38f, s = 0.f;
    for (int i = t * 8; i < VOC; i += 2048) {
        const u16x8 h8 = *(const u16x8*)&lg[i];
        #pragma unroll
        for (int j = 0; j < 8; ++j) {
            const float xv = bf2f(h8[j]);
            row[i + j] = xv;
            const float d = xv - m;
            if (d > 0.f) { s = s * __expf(-d) + 1.f; m = xv; }
            else         { s += __expf(d); }
        }
    }
    #pragma unroll
    for (int o = 32; o; o >>= 1) {
        const float om = __shfl_down(m, o, 64), os = __shfl_down(s, o, 64);
        const float M = fmaxf(m, om);
        s = s * __expf(m - M) + os * __expf(om - M);
        m = M;
    }
    if ((t & 63) == 0) { rm[t >> 6] = m; rs_[t >> 6] = s; }
    __syncthreads();
    const float M = fmaxf(fmaxf(rm[0], rm[1]), fmaxf(rm[2], rm[3]));
    const float S = rs_[0]*__expf(rm[0]-M) + rs_[1]*__expf(rm[1]-M)
                  + rs_[2]*__expf(rm[2]-M) + rs_[3]*__expf(rm[3]-M);
    const float inv = 1.f / S;
    for (int i = t * 4; i < VOC; i += 1024) {
        float4 v = *(const float4*)&row[i];
        v.x = __expf(v.x - M) * inv;
        v.y = __expf(v.y - M) * inv;
        v.z = __expf(v.z - M) * inv;
        v.w = __expf(v.w - M) * inv;
        *(float4*)&out[obase + i] = v;
    }
}

// ---- host-side orchestration -------------------------------------------
extern "C" void kernel_launch(void* const* d_in, const int* in_sizes, int n_in,
                              void* d_out, int out_size, void* d_ws, size_t ws_size,
                              hipStream_t stream)
{
    const int*   x    = (const int*)  d_in[0];
    const int*   lens = (const int*)  d_in[1];
    const float* emb  = (const float*)d_in[2];
    const float* Wq   = (const float*)d_in[3];
    const float* bq   = (const float*)d_in[4];
    const float* Wk   = (const float*)d_in[5];
    const float* bk   = (const float*)d_in[6];
    const float* Wv   = (const float*)d_in[7];
    const float* bv   = (const float*)d_in[8];
    const float* W1   = (const float*)d_in[9];
    const float* b1   = (const float*)d_in[10];
    const float* W2   = (const float*)d_in[11];
    const float* b2   = (const float*)d_in[12];
    const float* g1   = (const float*)d_in[13];
    const float* be1  = (const float*)d_in[14];
    const float* g2   = (const float*)d_in[15];
    const float* be2  = (const float*)d_in[16];
    const float* fcw  = (const float*)d_in[17];
    const float* fcb  = (const float*)d_in[18];

    float* out = (float*)d_out;
    float* Zb     = out;
    float* O1f    = Zb + NH;
    float* BQKV   = O1f + NH;                       // [L][2304]
    u16* ub     = (u16*)(BQKV + (long long)LAYERS * 2304);
    u16* Zbh    = ub;  ub += NH;
    u16* QKVh   = ub;  ub += (long long)NROWS * 1536; // Q|K, ldc 1536
    u16* SCOREH = ub;  ub += SS8;                   // bf16 scores
    u16* ATTB   = ub;  ub += SS8;
    u16* Vt     = ub;  ub += NH;                    // [B][H][S]
    u16* ATTO   = ub;  ub += NH;                    // attn-out / mid (bf16)
    u16* O1h    = ub;  ub += NH;
    u16* M1h    = ub;  ub += NH;
    u16* WT     = ub;  ub += 41LL * WSZ;

    u16* ZFh = (u16*)d_ws;
    u16* EH  = ZFh + NH;
    const bool ehpath = ws_size >= (size_t)((NH + (long long)VOC * HID) * 2);
    u16* LOGH = (u16*)out + VOC;                    // bf16 logits, ldc 2*VOC

    const float scale = 1.0f / sqrtf((float)HID);
    const dim3 blk(256), blk128(128);

    embed_kernel<<<NROWS, blk, 0, stream>>>(x, emb, Zb, Zbh);
    transp_all<<<dim3(24, 24, 41), blk, 0, stream>>>(Wq, Wk, Wv, W1, W2, fcw, WT);
    pack_bias_all<<<dim3(3, LAYERS), dim3(768), 0, stream>>>(bq, bk, bv, BQKV);
    if (ehpath) convert_emb<<<7500, blk, 0, stream>>>(emb, EH);

    for (int l = 0; l < LAYERS; ++l) {
        const u16* wl = WT + (long long)l * 5 * WSZ;

        // qkv: Q,K -> QKVh[4096][1536]; V -> Vt transposed.
        gemm_big<false, true><<<dim3(18, 32), blk, 0, stream>>>(
            Zbh, wl, QKVh, 1536, 2304, HID,
            BQKV + (long long)l * 2304, Vt);

        // scores = scale * Q @ K^T -> bf16
        gemm_small<false, true><<<dim3(8, 8, BATCH), blk128, 0, stream>>>(
            QKVh, 1536, (long long)SEQ * 1536,
            QKVh + 768, 1536, (long long)SEQ * 1536,
            SCOREH, SEQ, (long long)SEQ * SEQ,
            512, HID, nullptr, scale);

        softmax_q_kernel<<<dim3(BATCH, SEQ/16), blk, 0, stream>>>(SCOREH, ATTB, lens);

        // attnout = att @ V -> bf16 (only consumer is ln1)
        gemm_small<false, true><<<dim3(12, 8, BATCH), blk128, 0, stream>>>(
            ATTB, SEQ, (long long)SEQ * SEQ,
            Vt, SEQ, (long long)HID * SEQ,
            ATTO, HID, (long long)SEQ * HID,
            768, SEQ, nullptr, 1.0f);

        // o1 = LN(z + attnout)
        ln_add_b_kernel<<<NROWS/4, blk, 0, stream>>>(Zb, ATTO, O1f, O1h,
                                                     g1 + l*HID, be1 + l*HID);
        // mid1 = relu(o1 @ W1 + b1) -> bf16
        gemm_small<true, true><<<dim3(12, 64), blk128, 0, stream>>>(
            O1h, HID, 0, wl + 3*WSZ, HID, 0, M1h, HID, 0,
            768, HID, b1 + l*HID, 1.0f);
        // mid = mid1 @ W2 + b2 -> bf16 (only consumer is ln2)
        gemm_small<false, true><<<dim3(12, 64), blk128, 0, stream>>>(
            M1h, HID, 0, wl + 4*WSZ, HID, 0, ATTO, HID, 0,
            768, HID, b2 + l*HID, 1.0f);
        // z = LN(o1 + mid)
        ln_add_b_kernel<<<NROWS/4, blk, 0, stream>>>(O1f, ATTO, Zb, Zbh,
                                                     g2 + l*HID, be2 + l*HID);
    }

    // fc: zf = z @ fc_w + fc_b -> bf16 in d_ws
    gemm_small<false, true><<<dim3(12, 64), blk128, 0, stream>>>(
        Zbh, HID, 0, WT + 40LL*WSZ, HID, 0, ZFh, HID, 0,
        768, HID, fcb, 1.0f);

    // logits = zf @ emb^T -> bf16, row-local upper half of d_out.
    if (ehpath) {
        gemm_big<true, false><<<dim3(32, 79), blk, 0, stream>>>(
            ZFh, EH, LOGH, 2*VOC, VOC, HID, nullptr, nullptr);
    } else {
        gemm_conv<<<dim3(32, 79), blk, 0, stream>>>(ZFh, emb, LOGH);
    }

    softmax_v_kernel<<<NROWS, blk, 0, stream>>>(out);
}